// Round 1
// baseline (1298.085 us; speedup 1.0000x reference)
//
#include <hip/hip_runtime.h>
#include <hip/hip_bf16.h>

#define D_IN 128
#define D_OUT 64

// ---------------------------------------------------------------------------
// Order-preserving float<->uint encoding for atomicMax-based segment max.
// enc(f) monotone in float order; enc(anything finite or -inf) > 0, so
// memset(0) is a valid "-infinity" initializer.
__device__ __forceinline__ unsigned int enc_f32(float f) {
    unsigned int b = __float_as_uint(f);
    return (b & 0x80000000u) ? ~b : (b | 0x80000000u);
}
__device__ __forceinline__ float dec_f32(unsigned int u) {
    return (u & 0x80000000u) ? __uint_as_float(u ^ 0x80000000u)
                             : __uint_as_float(~u);
}

// ---------------------------------------------------------------------------
// K1: one wave (64 lanes) per node. lane j computes z[n][j] = h[n,:]·W[:,j],
// then wave-reduces es[n]=z[n]·a[:64], ed[n]=z[n]·a[64:].
__global__ __launch_bounds__(256) void k_project(
    const float* __restrict__ h, const float* __restrict__ W,
    const float* __restrict__ a, float* __restrict__ z,
    float* __restrict__ es, float* __restrict__ ed, int n_nodes)
{
    int wave = (blockIdx.x * blockDim.x + threadIdx.x) >> 6;
    int lane = threadIdx.x & 63;
    if (wave >= n_nodes) return;

    const float* hr = h + (size_t)wave * D_IN;
    float acc = 0.0f;
#pragma unroll 8
    for (int k = 0; k < D_IN; ++k) {
        acc = fmaf(hr[k], W[k * D_OUT + lane], acc);  // hr[k] wave-uniform, W coalesced+cached
    }
    z[(size_t)wave * D_OUT + lane] = acc;

    float pes = acc * a[lane];
    float ped = acc * a[D_OUT + lane];
#pragma unroll
    for (int off = 32; off > 0; off >>= 1) {
        pes += __shfl_down(pes, off, 64);
        ped += __shfl_down(ped, off, 64);
    }
    if (lane == 0) { es[wave] = pes; ed[wave] = ped; }
}

// ---------------------------------------------------------------------------
// K2: per-edge logit -> atomicMax into encoded per-dst max.
__global__ __launch_bounds__(256) void k_edge_max(
    const int* __restrict__ src, const int* __restrict__ dst,
    const float* __restrict__ es, const float* __restrict__ ed,
    unsigned int* __restrict__ m_enc, int n_edges)
{
    int e = blockIdx.x * blockDim.x + threadIdx.x;
    if (e >= n_edges) return;
    int d = dst[e];
    float ev = es[src[e]] + ed[d];
    atomicMax(&m_enc[d], enc_f32(ev));
}

// ---------------------------------------------------------------------------
// K3: per-edge exp(e - m[dst]) -> atomicAdd into per-dst denom.
__global__ __launch_bounds__(256) void k_edge_sum(
    const int* __restrict__ src, const int* __restrict__ dst,
    const float* __restrict__ es, const float* __restrict__ ed,
    const unsigned int* __restrict__ m_enc, float* __restrict__ s, int n_edges)
{
    int e = blockIdx.x * blockDim.x + threadIdx.x;
    if (e >= n_edges) return;
    int d = dst[e];
    float ev = es[src[e]] + ed[d];
    float m = dec_f32(m_enc[d]);
    atomicAdd(&s[d], __expf(ev - m));
}

// ---------------------------------------------------------------------------
// K4: one wave per edge; lane j scatters alpha * z[src][j] into out[dst][j].
__global__ __launch_bounds__(256) void k_scatter(
    const int* __restrict__ src, const int* __restrict__ dst,
    const float* __restrict__ es, const float* __restrict__ ed,
    const unsigned int* __restrict__ m_enc, const float* __restrict__ s,
    const float* __restrict__ z, float* __restrict__ out, int n_edges)
{
    int e = (int)((blockIdx.x * (size_t)blockDim.x + threadIdx.x) >> 6);
    int lane = threadIdx.x & 63;
    if (e >= n_edges) return;

    int sn = src[e];           // wave-uniform (broadcast load)
    int dn = dst[e];
    float ev = es[sn] + ed[dn];
    float m = dec_f32(m_enc[dn]);
    float alpha = __expf(ev - m) / s[dn];

    float v = alpha * z[(size_t)sn * D_OUT + lane];  // coalesced 256B/wave
    atomicAdd(&out[(size_t)dn * D_OUT + lane], v);   // coalesced 256B/wave
}

// ---------------------------------------------------------------------------
extern "C" void kernel_launch(void* const* d_in, const int* in_sizes, int n_in,
                              void* d_out, int out_size, void* d_ws, size_t ws_size,
                              hipStream_t stream) {
    const float* h   = (const float*)d_in[0];
    const float* W   = (const float*)d_in[1];
    const float* a   = (const float*)d_in[2];
    const int*   src = (const int*)d_in[3];
    const int*   dst = (const int*)d_in[4];
    float* out = (float*)d_out;

    const int n_nodes = in_sizes[0] / D_IN;   // 100000
    const int n_edges = in_sizes[3];          // 3200000

    // workspace carve-up (~27.2 MB)
    char* w = (char*)d_ws;
    float*        z     = (float*)w;        w += (size_t)n_nodes * D_OUT * sizeof(float);
    float*        es    = (float*)w;        w += (size_t)n_nodes * sizeof(float);
    float*        ed    = (float*)w;        w += (size_t)n_nodes * sizeof(float);
    unsigned int* m_enc = (unsigned int*)w; w += (size_t)n_nodes * sizeof(unsigned int);
    float*        s     = (float*)w;        w += (size_t)n_nodes * sizeof(float);

    hipMemsetAsync(d_out, 0, (size_t)n_nodes * D_OUT * sizeof(float), stream);
    hipMemsetAsync(m_enc, 0, (size_t)n_nodes * sizeof(unsigned int), stream);
    hipMemsetAsync(s,     0, (size_t)n_nodes * sizeof(float), stream);

    // K1: projection — one wave per node, 4 waves per block
    {
        int blocks = (n_nodes + 3) / 4;
        k_project<<<blocks, 256, 0, stream>>>(h, W, a, z, es, ed, n_nodes);
    }
    // K2: segment max
    {
        int blocks = (n_edges + 255) / 256;
        k_edge_max<<<blocks, 256, 0, stream>>>(src, dst, es, ed, m_enc, n_edges);
    }
    // K3: segment sum of exp
    {
        int blocks = (n_edges + 255) / 256;
        k_edge_sum<<<blocks, 256, 0, stream>>>(src, dst, es, ed, m_enc, s, n_edges);
    }
    // K4: weighted scatter — one wave per edge, 4 edges per block
    {
        long long waves = n_edges;
        int blocks = (int)((waves + 3) / 4);
        k_scatter<<<blocks, 256, 0, stream>>>(src, dst, es, ed, m_enc, s, z, out, n_edges);
    }
}

// Round 2
// 973.265 us; speedup vs baseline: 1.3337x; 1.3337x over previous
//
#include <hip/hip_runtime.h>

#define D_IN 128
#define D_OUT 64
#define SCAN_ITEMS 2048   // per scan block: 256 threads x 8 items

// ---------------------------------------------------------------------------
// K1: one wave per node. lane j computes z[n][j] = h[n,:]·W[:,j],
// then wave-reduces es[n]=z[n]·a[:64], ed[n]=z[n]·a[64:].
__global__ __launch_bounds__(256) void k_project(
    const float* __restrict__ h, const float* __restrict__ W,
    const float* __restrict__ a, float* __restrict__ z,
    float* __restrict__ es, float* __restrict__ ed, int n_nodes)
{
    int wave = (blockIdx.x * blockDim.x + threadIdx.x) >> 6;
    int lane = threadIdx.x & 63;
    if (wave >= n_nodes) return;

    const float* hr = h + (size_t)wave * D_IN;
    float acc = 0.0f;
#pragma unroll 8
    for (int k = 0; k < D_IN; ++k)
        acc = fmaf(hr[k], W[k * D_OUT + lane], acc);  // hr[k] broadcast, W in L1
    z[(size_t)wave * D_OUT + lane] = acc;

    float pes = acc * a[lane];
    float ped = acc * a[D_OUT + lane];
#pragma unroll
    for (int off = 32; off > 0; off >>= 1) {
        pes += __shfl_down(pes, off, 64);
        ped += __shfl_down(ped, off, 64);
    }
    if (lane == 0) { es[wave] = pes; ed[wave] = ped; }
}

// ---------------------------------------------------------------------------
// CSR build: histogram of dst
__global__ __launch_bounds__(256) void k_count(
    const int* __restrict__ dst, unsigned int* __restrict__ count, int n_edges)
{
    int e = blockIdx.x * blockDim.x + threadIdx.x;
    if (e < n_edges) atomicAdd(&count[dst[e]], 1u);
}

// Exclusive scan, level 1: each block scans SCAN_ITEMS counts.
__global__ __launch_bounds__(256) void k_scan1(
    const unsigned int* __restrict__ count, unsigned int* __restrict__ off,
    unsigned int* __restrict__ blk_sums, int n)
{
    __shared__ unsigned int tmp[256];
    int tid = threadIdx.x;
    int base = blockIdx.x * SCAN_ITEMS;
    unsigned int v[8]; unsigned int tsum = 0;
#pragma unroll
    for (int i = 0; i < 8; ++i) {
        int idx = base + tid * 8 + i;
        v[i] = (idx < n) ? count[idx] : 0u;
        tsum += v[i];
    }
    tmp[tid] = tsum; __syncthreads();
    for (int o = 1; o < 256; o <<= 1) {
        unsigned int u = (tid >= o) ? tmp[tid - o] : 0u; __syncthreads();
        tmp[tid] += u; __syncthreads();
    }
    unsigned int run = tmp[tid] - tsum;  // exclusive prefix of this thread
    if (tid == 255) blk_sums[blockIdx.x] = tmp[255];
#pragma unroll
    for (int i = 0; i < 8; ++i) {
        int idx = base + tid * 8 + i;
        if (idx < n) off[idx] = run;
        run += v[i];
    }
}

// Level 2: single block scans the (<=256) block sums; writes off[n]=total.
__global__ __launch_bounds__(256) void k_scan2(
    const unsigned int* __restrict__ blk_sums, unsigned int* __restrict__ blk_offs,
    unsigned int* __restrict__ off, int nblocks, int n)
{
    __shared__ unsigned int tmp[256];
    int tid = threadIdx.x;
    unsigned int v = (tid < nblocks) ? blk_sums[tid] : 0u;
    tmp[tid] = v; __syncthreads();
    for (int o = 1; o < 256; o <<= 1) {
        unsigned int u = (tid >= o) ? tmp[tid - o] : 0u; __syncthreads();
        tmp[tid] += u; __syncthreads();
    }
    if (tid < nblocks) blk_offs[tid] = tmp[tid] - v;
    if (tid == 255) off[n] = tmp[255];  // total == n_edges
}

// Level 3: add block offsets; also duplicate into cursor for the fill pass.
__global__ __launch_bounds__(256) void k_scan3(
    unsigned int* __restrict__ off, unsigned int* __restrict__ cursor,
    const unsigned int* __restrict__ blk_offs, int n)
{
    int i = blockIdx.x * blockDim.x + threadIdx.x;
    if (i < n) {
        unsigned int o = off[i] + blk_offs[i / SCAN_ITEMS];
        off[i] = o; cursor[i] = o;
    }
}

// Fill: ssrc[pos] = src[e], pos grouped by dst (order within group arbitrary).
__global__ __launch_bounds__(256) void k_fill(
    const int* __restrict__ src, const int* __restrict__ dst,
    unsigned int* __restrict__ cursor, int* __restrict__ ssrc, int n_edges)
{
    int e = blockIdx.x * blockDim.x + threadIdx.x;
    if (e < n_edges) {
        unsigned int pos = atomicAdd(&cursor[dst[e]], 1u);
        ssrc[pos] = src[e];
    }
}

// ---------------------------------------------------------------------------
// Fused softmax + weighted gather: one wave per dst node, register accumulate,
// single 256B row write. No atomics.
__global__ __launch_bounds__(256) void k_fused(
    const int* __restrict__ ssrc, const unsigned int* __restrict__ off,
    const float* __restrict__ es, const float* __restrict__ ed,
    const float* __restrict__ z, float* __restrict__ out, int n_nodes)
{
    int node = (blockIdx.x * blockDim.x + threadIdx.x) >> 6;
    int lane = threadIdx.x & 63;
    if (node >= n_nodes) return;

    unsigned int start = off[node], end = off[node + 1];
    float* orow = out + (size_t)node * D_OUT;
    if (start == end) { orow[lane] = 0.0f; return; }  // no in-edges -> 0 (DGL)

    float edd = ed[node];

    // phase 1a: lane-strided max over segment (es gathers are L2-resident, 400KB)
    float m = -INFINITY;
    for (unsigned int i = start + lane; i < end; i += 64)
        m = fmaxf(m, es[ssrc[i]] + edd);
#pragma unroll
    for (int o = 32; o > 0; o >>= 1) m = fmaxf(m, __shfl_xor(m, o, 64));

    // phase 1b: lane-strided sum of exp
    float ssum = 0.0f;
    for (unsigned int i = start + lane; i < end; i += 64)
        ssum += __expf(es[ssrc[i]] + edd - m);
#pragma unroll
    for (int o = 32; o > 0; o >>= 1) ssum += __shfl_xor(ssum, o, 64);
    float inv_s = 1.0f / ssum;

    // phase 2: serial over edges; broadcast loads for sn/es, coalesced z gather
    float acc = 0.0f;
    for (unsigned int i = start; i < end; ++i) {
        int sn = ssrc[i];                                  // wave-broadcast
        float alpha = __expf(es[sn] + edd - m) * inv_s;    // wave-uniform
        acc = fmaf(alpha, z[(size_t)sn * D_OUT + lane], acc);  // 256B coalesced
    }
    orow[lane] = acc;
}

// ---------------------------------------------------------------------------
extern "C" void kernel_launch(void* const* d_in, const int* in_sizes, int n_in,
                              void* d_out, int out_size, void* d_ws, size_t ws_size,
                              hipStream_t stream) {
    const float* h   = (const float*)d_in[0];
    const float* W   = (const float*)d_in[1];
    const float* a   = (const float*)d_in[2];
    const int*   src = (const int*)d_in[3];
    const int*   dst = (const int*)d_in[4];
    float* out = (float*)d_out;

    const int n_nodes = in_sizes[0] / D_IN;   // 100000
    const int n_edges = in_sizes[3];          // 3200000

    // workspace carve-up (~40 MB), 256B-aligned chunks
    auto align = [](size_t x) { return (x + 255) & ~(size_t)255; };
    char* w = (char*)d_ws;
    float* z = (float*)w;              w += align((size_t)n_nodes * D_OUT * sizeof(float));
    float* es = (float*)w;             w += align((size_t)n_nodes * sizeof(float));
    float* ed = (float*)w;             w += align((size_t)n_nodes * sizeof(float));
    unsigned int* count = (unsigned int*)w;  w += align((size_t)n_nodes * sizeof(unsigned int));
    unsigned int* off = (unsigned int*)w;    w += align(((size_t)n_nodes + 1) * sizeof(unsigned int));
    unsigned int* cursor = (unsigned int*)w; w += align((size_t)n_nodes * sizeof(unsigned int));
    unsigned int* blk_sums = (unsigned int*)w; w += align(256 * sizeof(unsigned int));
    unsigned int* blk_offs = (unsigned int*)w; w += align(256 * sizeof(unsigned int));
    int* ssrc = (int*)w;               w += align((size_t)n_edges * sizeof(int));

    hipMemsetAsync(count, 0, (size_t)n_nodes * sizeof(unsigned int), stream);

    // K1: projection
    k_project<<<(n_nodes + 3) / 4, 256, 0, stream>>>(h, W, a, z, es, ed, n_nodes);

    // CSR build
    k_count<<<(n_edges + 255) / 256, 256, 0, stream>>>(dst, count, n_edges);
    int scan_blocks = (n_nodes + SCAN_ITEMS - 1) / SCAN_ITEMS;   // 49 for N=100k
    k_scan1<<<scan_blocks, 256, 0, stream>>>(count, off, blk_sums, n_nodes);
    k_scan2<<<1, 256, 0, stream>>>(blk_sums, blk_offs, off, scan_blocks, n_nodes);
    k_scan3<<<(n_nodes + 255) / 256, 256, 0, stream>>>(off, cursor, blk_offs, n_nodes);
    k_fill<<<(n_edges + 255) / 256, 256, 0, stream>>>(src, dst, cursor, ssrc, n_edges);

    // Fused softmax + gather: one wave per node
    k_fused<<<(n_nodes + 3) / 4, 256, 0, stream>>>(ssrc, off, es, ed, z, out, n_nodes);
}

// Round 3
// 634.104 us; speedup vs baseline: 2.0471x; 1.5349x over previous
//
#include <hip/hip_runtime.h>

#define D_IN 128
#define D_OUT 64
#define SCAN_ITEMS 2048   // per scan block: 256 threads x 8 items

// ---------------------------------------------------------------------------
// K1: one wave per node. lane j computes z[n][j] = h[n,:]·W[:,j],
// then wave-reduces es[n]=z[n]·a[:64], ed[n]=z[n]·a[64:].
__global__ __launch_bounds__(256) void k_project(
    const float* __restrict__ h, const float* __restrict__ W,
    const float* __restrict__ a, float* __restrict__ z,
    float* __restrict__ es, float* __restrict__ ed, int n_nodes)
{
    int wave = (blockIdx.x * blockDim.x + threadIdx.x) >> 6;
    int lane = threadIdx.x & 63;
    if (wave >= n_nodes) return;

    const float* hr = h + (size_t)wave * D_IN;
    float acc = 0.0f;
#pragma unroll 8
    for (int k = 0; k < D_IN; ++k)
        acc = fmaf(hr[k], W[k * D_OUT + lane], acc);  // hr[k] broadcast, W in L1
    z[(size_t)wave * D_OUT + lane] = acc;

    float pes = acc * a[lane];
    float ped = acc * a[D_OUT + lane];
#pragma unroll
    for (int off = 32; off > 0; off >>= 1) {
        pes += __shfl_down(pes, off, 64);
        ped += __shfl_down(ped, off, 64);
    }
    if (lane == 0) { es[wave] = pes; ed[wave] = ped; }
}

// ---------------------------------------------------------------------------
// Rank path: one atomic pass assigns per-edge rank within its dst segment
// AND builds the histogram in count[].
__global__ __launch_bounds__(256) void k_rank(
    const int* __restrict__ dst, unsigned int* __restrict__ count,
    unsigned int* __restrict__ rank, int n_edges)
{
    int e = blockIdx.x * blockDim.x + threadIdx.x;
    if (e < n_edges) rank[e] = atomicAdd(&count[dst[e]], 1u);
}

// Atomic-free placement: pos = off[dst] + rank.
__global__ __launch_bounds__(256) void k_place(
    const int* __restrict__ src, const int* __restrict__ dst,
    const unsigned int* __restrict__ off, const unsigned int* __restrict__ rank,
    int* __restrict__ ssrc, int n_edges)
{
    int e = blockIdx.x * blockDim.x + threadIdx.x;
    if (e < n_edges) ssrc[off[dst[e]] + rank[e]] = src[e];
}

// Fallback path (small ws): histogram only.
__global__ __launch_bounds__(256) void k_count(
    const int* __restrict__ dst, unsigned int* __restrict__ count, int n_edges)
{
    int e = blockIdx.x * blockDim.x + threadIdx.x;
    if (e < n_edges) atomicAdd(&count[dst[e]], 1u);
}

// Fallback fill: atomic cursor.
__global__ __launch_bounds__(256) void k_fill(
    const int* __restrict__ src, const int* __restrict__ dst,
    unsigned int* __restrict__ cursor, int* __restrict__ ssrc, int n_edges)
{
    int e = blockIdx.x * blockDim.x + threadIdx.x;
    if (e < n_edges) {
        unsigned int pos = atomicAdd(&cursor[dst[e]], 1u);
        ssrc[pos] = src[e];
    }
}

// ---------------------------------------------------------------------------
// Exclusive scan, level 1: each block scans SCAN_ITEMS counts.
__global__ __launch_bounds__(256) void k_scan1(
    const unsigned int* __restrict__ count, unsigned int* __restrict__ off,
    unsigned int* __restrict__ blk_sums, int n)
{
    __shared__ unsigned int tmp[256];
    int tid = threadIdx.x;
    int base = blockIdx.x * SCAN_ITEMS;
    unsigned int v[8]; unsigned int tsum = 0;
#pragma unroll
    for (int i = 0; i < 8; ++i) {
        int idx = base + tid * 8 + i;
        v[i] = (idx < n) ? count[idx] : 0u;
        tsum += v[i];
    }
    tmp[tid] = tsum; __syncthreads();
    for (int o = 1; o < 256; o <<= 1) {
        unsigned int u = (tid >= o) ? tmp[tid - o] : 0u; __syncthreads();
        tmp[tid] += u; __syncthreads();
    }
    unsigned int run = tmp[tid] - tsum;  // exclusive prefix of this thread
    if (tid == 255) blk_sums[blockIdx.x] = tmp[255];
#pragma unroll
    for (int i = 0; i < 8; ++i) {
        int idx = base + tid * 8 + i;
        if (idx < n) off[idx] = run;
        run += v[i];
    }
}

// Level 2: single block scans the (<=256) block sums; writes off[n]=total.
__global__ __launch_bounds__(256) void k_scan2(
    const unsigned int* __restrict__ blk_sums, unsigned int* __restrict__ blk_offs,
    unsigned int* __restrict__ off, int nblocks, int n)
{
    __shared__ unsigned int tmp[256];
    int tid = threadIdx.x;
    unsigned int v = (tid < nblocks) ? blk_sums[tid] : 0u;
    tmp[tid] = v; __syncthreads();
    for (int o = 1; o < 256; o <<= 1) {
        unsigned int u = (tid >= o) ? tmp[tid - o] : 0u; __syncthreads();
        tmp[tid] += u; __syncthreads();
    }
    if (tid < nblocks) blk_offs[tid] = tmp[tid] - v;
    if (tid == 255) off[n] = tmp[255];  // total == n_edges
}

// Level 3: add block offsets; duplicate into cursor (reused count array —
// only consumed by the fallback k_fill).
__global__ __launch_bounds__(256) void k_scan3(
    unsigned int* __restrict__ off, unsigned int* __restrict__ cursor,
    const unsigned int* __restrict__ blk_offs, int n)
{
    int i = blockIdx.x * blockDim.x + threadIdx.x;
    if (i < n) {
        unsigned int o = off[i] + blk_offs[i / SCAN_ITEMS];
        off[i] = o; cursor[i] = o;
    }
}

// ---------------------------------------------------------------------------
// Fused softmax + weighted gather: one wave per dst node.
// Phase 2: 4 edges per iteration — 16 lanes per edge, float4 per lane
// (1 KB of z-row payload per load instruction). No atomics.
__global__ __launch_bounds__(256) void k_fused(
    const int* __restrict__ ssrc, const unsigned int* __restrict__ off,
    const float* __restrict__ es, const float* __restrict__ ed,
    const float* __restrict__ z, float* __restrict__ out, int n_nodes)
{
    int node = (blockIdx.x * blockDim.x + threadIdx.x) >> 6;
    int lane = threadIdx.x & 63;
    if (node >= n_nodes) return;
    int g  = lane >> 4;   // edge group 0..3
    int fl = lane & 15;   // feature lane: features [4*fl, 4*fl+4)

    unsigned int start = off[node], end = off[node + 1];
    float* orow = out + (size_t)node * D_OUT;
    if (start == end) {   // no in-edges -> 0 (DGL)
        if (g == 0) *(float4*)(orow + fl * 4) = make_float4(0.f, 0.f, 0.f, 0.f);
        return;
    }

    float edd = ed[node];

    // phase 1a: lane-strided max (es gathers are L2-resident, 400KB)
    float m = -INFINITY;
    for (unsigned int i = start + lane; i < end; i += 64)
        m = fmaxf(m, es[ssrc[i]] + edd);
#pragma unroll
    for (int o = 32; o > 0; o >>= 1) m = fmaxf(m, __shfl_xor(m, o, 64));

    // phase 1b: lane-strided sum of exp
    float ssum = 0.0f;
    for (unsigned int i = start + lane; i < end; i += 64)
        ssum += __expf(es[ssrc[i]] + edd - m);
#pragma unroll
    for (int o = 32; o > 0; o >>= 1) ssum += __shfl_xor(ssum, o, 64);
    float inv_s = 1.0f / ssum;

    // phase 2: 4 edges in flight per iteration
    float4 acc = make_float4(0.f, 0.f, 0.f, 0.f);
    for (unsigned int i = start + g; i < end; i += 4) {
        int sn = ssrc[i];                                  // 16B/wave, group-broadcast
        float alpha = __expf(es[sn] + edd - m) * inv_s;    // group-uniform
        const float4 v = *(const float4*)(z + (size_t)sn * D_OUT + fl * 4);
        acc.x = fmaf(alpha, v.x, acc.x);
        acc.y = fmaf(alpha, v.y, acc.y);
        acc.z = fmaf(alpha, v.z, acc.z);
        acc.w = fmaf(alpha, v.w, acc.w);
    }
    // reduce the 4 edge-groups: lanes {l, l^16, l^32, l^48}
#pragma unroll
    for (int o = 16; o <= 32; o <<= 1) {
        acc.x += __shfl_xor(acc.x, o, 64);
        acc.y += __shfl_xor(acc.y, o, 64);
        acc.z += __shfl_xor(acc.z, o, 64);
        acc.w += __shfl_xor(acc.w, o, 64);
    }
    if (g == 0) *(float4*)(orow + fl * 4) = acc;
}

// ---------------------------------------------------------------------------
extern "C" void kernel_launch(void* const* d_in, const int* in_sizes, int n_in,
                              void* d_out, int out_size, void* d_ws, size_t ws_size,
                              hipStream_t stream) {
    const float* h   = (const float*)d_in[0];
    const float* W   = (const float*)d_in[1];
    const float* a   = (const float*)d_in[2];
    const int*   src = (const int*)d_in[3];
    const int*   dst = (const int*)d_in[4];
    float* out = (float*)d_out;

    const int n_nodes = in_sizes[0] / D_IN;   // 100000
    const int n_edges = in_sizes[3];          // 3200000

    auto align = [](size_t x) { return (x + 255) & ~(size_t)255; };
    char* w = (char*)d_ws;
    float* z  = (float*)w;                 w += align((size_t)n_nodes * D_OUT * sizeof(float));
    float* es = (float*)w;                 w += align((size_t)n_nodes * sizeof(float));
    float* ed = (float*)w;                 w += align((size_t)n_nodes * sizeof(float));
    unsigned int* count = (unsigned int*)w;  w += align((size_t)n_nodes * sizeof(unsigned int));
    unsigned int* off   = (unsigned int*)w;  w += align(((size_t)n_nodes + 1) * sizeof(unsigned int));
    unsigned int* blk_sums = (unsigned int*)w; w += align(256 * sizeof(unsigned int));
    unsigned int* blk_offs = (unsigned int*)w; w += align(256 * sizeof(unsigned int));
    int* ssrc = (int*)w;                   w += align((size_t)n_edges * sizeof(int));
    unsigned int* rank = (unsigned int*)w; // optional tail
    size_t need_rank = ((char*)rank - (char*)d_ws) + align((size_t)n_edges * sizeof(unsigned int));
    const bool use_rank = (ws_size >= need_rank);   // constant across calls: graph-safe

    hipMemsetAsync(count, 0, (size_t)n_nodes * sizeof(unsigned int), stream);

    // K1: projection
    k_project<<<(n_nodes + 3) / 4, 256, 0, stream>>>(h, W, a, z, es, ed, n_nodes);

    const int eblocks = (n_edges + 255) / 256;
    const int scan_blocks = (n_nodes + SCAN_ITEMS - 1) / SCAN_ITEMS;   // 49 for N=100k

    if (use_rank) {
        // single atomic pass: histogram + per-edge rank
        k_rank<<<eblocks, 256, 0, stream>>>(dst, count, rank, n_edges);
        k_scan1<<<scan_blocks, 256, 0, stream>>>(count, off, blk_sums, n_nodes);
        k_scan2<<<1, 256, 0, stream>>>(blk_sums, blk_offs, off, scan_blocks, n_nodes);
        k_scan3<<<(n_nodes + 255) / 256, 256, 0, stream>>>(off, count, blk_offs, n_nodes);
        // atomic-free placement
        k_place<<<eblocks, 256, 0, stream>>>(src, dst, off, rank, ssrc, n_edges);
    } else {
        // fallback: two atomic passes (round-2 scheme), cursor aliases count
        k_count<<<eblocks, 256, 0, stream>>>(dst, count, n_edges);
        k_scan1<<<scan_blocks, 256, 0, stream>>>(count, off, blk_sums, n_nodes);
        k_scan2<<<1, 256, 0, stream>>>(blk_sums, blk_offs, off, scan_blocks, n_nodes);
        k_scan3<<<(n_nodes + 255) / 256, 256, 0, stream>>>(off, count, blk_offs, n_nodes);
        k_fill<<<eblocks, 256, 0, stream>>>(src, dst, count, ssrc, n_edges);
    }

    // Fused softmax + gather: one wave per node, 4 nodes per block
    k_fused<<<(n_nodes + 3) / 4, 256, 0, stream>>>(ssrc, off, es, ed, z, out, n_nodes);
}

// Round 4
// 564.544 us; speedup vs baseline: 2.2994x; 1.1232x over previous
//
#include <hip/hip_runtime.h>

#define D_IN 128
#define D_OUT 64
#define SCAN_ITEMS 2048   // per scan block: 256 threads x 8 items
#define NPW 8             // nodes per wave in k_project

// ---------------------------------------------------------------------------
// K1: 8 nodes per wave, lane = output column. Per 4-k step: 4 coalesced W
// loads + 8 broadcast float4 h loads feed 32 FMAs (8 independent chains).
// Epilogue: coalesced z stores + wave-reduced es/ed.
__global__ __launch_bounds__(256) void k_project(
    const float* __restrict__ h, const float* __restrict__ W,
    const float* __restrict__ a, float* __restrict__ z,
    float* __restrict__ es, float* __restrict__ ed, int n_nodes)
{
    int wave = (blockIdx.x * blockDim.x + threadIdx.x) >> 6;
    int lane = threadIdx.x & 63;
    int n0 = wave * NPW;
    if (n0 >= n_nodes) return;
    int nv = min(NPW, n_nodes - n0);   // valid nodes in this batch

    // clamped row pointers (tail batch reads row nv-1 redundantly, discarded)
    const float* hr[NPW];
#pragma unroll
    for (int n = 0; n < NPW; ++n)
        hr[n] = h + (size_t)(n0 + min(n, nv - 1)) * D_IN;

    float acc[NPW];
#pragma unroll
    for (int n = 0; n < NPW; ++n) acc[n] = 0.0f;

    for (int k4 = 0; k4 < D_IN / 4; ++k4) {
        float4 wk;                                   // W[k..k+3][lane], coalesced
        wk.x = W[(4 * k4 + 0) * D_OUT + lane];
        wk.y = W[(4 * k4 + 1) * D_OUT + lane];
        wk.z = W[(4 * k4 + 2) * D_OUT + lane];
        wk.w = W[(4 * k4 + 3) * D_OUT + lane];
#pragma unroll
        for (int n = 0; n < NPW; ++n) {
            const float4 hv = *(const float4*)(hr[n] + 4 * k4);  // wave-broadcast 16B
            acc[n] = fmaf(hv.x, wk.x, acc[n]);
            acc[n] = fmaf(hv.y, wk.y, acc[n]);
            acc[n] = fmaf(hv.z, wk.z, acc[n]);
            acc[n] = fmaf(hv.w, wk.w, acc[n]);
        }
    }

    float av  = a[lane];
    float av2 = a[D_OUT + lane];
#pragma unroll
    for (int n = 0; n < NPW; ++n) {
        if (n < nv) z[(size_t)(n0 + n) * D_OUT + lane] = acc[n];  // 256B coalesced
        float pes = acc[n] * av;
        float ped = acc[n] * av2;
#pragma unroll
        for (int o = 32; o > 0; o >>= 1) {
            pes += __shfl_down(pes, o, 64);
            ped += __shfl_down(ped, o, 64);
        }
        if (lane == 0 && n < nv) { es[n0 + n] = pes; ed[n0 + n] = ped; }
    }
}

// ---------------------------------------------------------------------------
// Rank path: one atomic pass assigns per-edge rank within its dst segment
// AND builds the histogram in count[].
__global__ __launch_bounds__(256) void k_rank(
    const int* __restrict__ dst, unsigned int* __restrict__ count,
    unsigned int* __restrict__ rank, int n_edges)
{
    int e = blockIdx.x * blockDim.x + threadIdx.x;
    if (e < n_edges) rank[e] = atomicAdd(&count[dst[e]], 1u);
}

// Atomic-free placement: pos = off[dst] + rank.
__global__ __launch_bounds__(256) void k_place(
    const int* __restrict__ src, const int* __restrict__ dst,
    const unsigned int* __restrict__ off, const unsigned int* __restrict__ rank,
    int* __restrict__ ssrc, int n_edges)
{
    int e = blockIdx.x * blockDim.x + threadIdx.x;
    if (e < n_edges) ssrc[off[dst[e]] + rank[e]] = src[e];
}

// Fallback path (small ws): histogram only.
__global__ __launch_bounds__(256) void k_count(
    const int* __restrict__ dst, unsigned int* __restrict__ count, int n_edges)
{
    int e = blockIdx.x * blockDim.x + threadIdx.x;
    if (e < n_edges) atomicAdd(&count[dst[e]], 1u);
}

// Fallback fill: atomic cursor.
__global__ __launch_bounds__(256) void k_fill(
    const int* __restrict__ src, const int* __restrict__ dst,
    unsigned int* __restrict__ cursor, int* __restrict__ ssrc, int n_edges)
{
    int e = blockIdx.x * blockDim.x + threadIdx.x;
    if (e < n_edges) {
        unsigned int pos = atomicAdd(&cursor[dst[e]], 1u);
        ssrc[pos] = src[e];
    }
}

// ---------------------------------------------------------------------------
// Exclusive scan, level 1: each block scans SCAN_ITEMS counts.
__global__ __launch_bounds__(256) void k_scan1(
    const unsigned int* __restrict__ count, unsigned int* __restrict__ off,
    unsigned int* __restrict__ blk_sums, int n)
{
    __shared__ unsigned int tmp[256];
    int tid = threadIdx.x;
    int base = blockIdx.x * SCAN_ITEMS;
    unsigned int v[8]; unsigned int tsum = 0;
#pragma unroll
    for (int i = 0; i < 8; ++i) {
        int idx = base + tid * 8 + i;
        v[i] = (idx < n) ? count[idx] : 0u;
        tsum += v[i];
    }
    tmp[tid] = tsum; __syncthreads();
    for (int o = 1; o < 256; o <<= 1) {
        unsigned int u = (tid >= o) ? tmp[tid - o] : 0u; __syncthreads();
        tmp[tid] += u; __syncthreads();
    }
    unsigned int run = tmp[tid] - tsum;  // exclusive prefix of this thread
    if (tid == 255) blk_sums[blockIdx.x] = tmp[255];
#pragma unroll
    for (int i = 0; i < 8; ++i) {
        int idx = base + tid * 8 + i;
        if (idx < n) off[idx] = run;
        run += v[i];
    }
}

// Level 2: single block scans the (<=256) block sums; writes off[n]=total.
__global__ __launch_bounds__(256) void k_scan2(
    const unsigned int* __restrict__ blk_sums, unsigned int* __restrict__ blk_offs,
    unsigned int* __restrict__ off, int nblocks, int n)
{
    __shared__ unsigned int tmp[256];
    int tid = threadIdx.x;
    unsigned int v = (tid < nblocks) ? blk_sums[tid] : 0u;
    tmp[tid] = v; __syncthreads();
    for (int o = 1; o < 256; o <<= 1) {
        unsigned int u = (tid >= o) ? tmp[tid - o] : 0u; __syncthreads();
        tmp[tid] += u; __syncthreads();
    }
    if (tid < nblocks) blk_offs[tid] = tmp[tid] - v;
    if (tid == 255) off[n] = tmp[255];  // total == n_edges
}

// Level 3: add block offsets; duplicate into cursor (consumed only by fallback).
__global__ __launch_bounds__(256) void k_scan3(
    unsigned int* __restrict__ off, unsigned int* __restrict__ cursor,
    const unsigned int* __restrict__ blk_offs, int n)
{
    int i = blockIdx.x * blockDim.x + threadIdx.x;
    if (i < n) {
        unsigned int o = off[i] + blk_offs[i / SCAN_ITEMS];
        off[i] = o; cursor[i] = o;
    }
}

// ---------------------------------------------------------------------------
// Fused softmax + weighted gather: one wave per dst node.
// Phase 2: 4 edges per iteration — 16 lanes per edge, float4 per lane.
__global__ __launch_bounds__(256) void k_fused(
    const int* __restrict__ ssrc, const unsigned int* __restrict__ off,
    const float* __restrict__ es, const float* __restrict__ ed,
    const float* __restrict__ z, float* __restrict__ out, int n_nodes)
{
    int node = (blockIdx.x * blockDim.x + threadIdx.x) >> 6;
    int lane = threadIdx.x & 63;
    if (node >= n_nodes) return;
    int g  = lane >> 4;   // edge group 0..3
    int fl = lane & 15;   // feature lane: features [4*fl, 4*fl+4)

    unsigned int start = off[node], end = off[node + 1];
    float* orow = out + (size_t)node * D_OUT;
    if (start == end) {   // no in-edges -> 0 (DGL)
        if (g == 0) *(float4*)(orow + fl * 4) = make_float4(0.f, 0.f, 0.f, 0.f);
        return;
    }

    float edd = ed[node];

    // phase 1a: lane-strided max (es gathers are L2-resident, 400KB)
    float m = -INFINITY;
    for (unsigned int i = start + lane; i < end; i += 64)
        m = fmaxf(m, es[ssrc[i]] + edd);
#pragma unroll
    for (int o = 32; o > 0; o >>= 1) m = fmaxf(m, __shfl_xor(m, o, 64));

    // phase 1b: lane-strided sum of exp
    float ssum = 0.0f;
    for (unsigned int i = start + lane; i < end; i += 64)
        ssum += __expf(es[ssrc[i]] + edd - m);
#pragma unroll
    for (int o = 32; o > 0; o >>= 1) ssum += __shfl_xor(ssum, o, 64);
    float inv_s = 1.0f / ssum;

    // phase 2: 4 edges in flight per iteration
    float4 acc = make_float4(0.f, 0.f, 0.f, 0.f);
    for (unsigned int i = start + g; i < end; i += 4) {
        int sn = ssrc[i];                                  // 16B/wave, group-broadcast
        float alpha = __expf(es[sn] + edd - m) * inv_s;    // group-uniform
        const float4 v = *(const float4*)(z + (size_t)sn * D_OUT + fl * 4);
        acc.x = fmaf(alpha, v.x, acc.x);
        acc.y = fmaf(alpha, v.y, acc.y);
        acc.z = fmaf(alpha, v.z, acc.z);
        acc.w = fmaf(alpha, v.w, acc.w);
    }
    // reduce the 4 edge-groups: lanes {l, l^16, l^32, l^48}
#pragma unroll
    for (int o = 16; o <= 32; o <<= 1) {
        acc.x += __shfl_xor(acc.x, o, 64);
        acc.y += __shfl_xor(acc.y, o, 64);
        acc.z += __shfl_xor(acc.z, o, 64);
        acc.w += __shfl_xor(acc.w, o, 64);
    }
    if (g == 0) *(float4*)(orow + fl * 4) = acc;
}

// ---------------------------------------------------------------------------
extern "C" void kernel_launch(void* const* d_in, const int* in_sizes, int n_in,
                              void* d_out, int out_size, void* d_ws, size_t ws_size,
                              hipStream_t stream) {
    const float* h   = (const float*)d_in[0];
    const float* W   = (const float*)d_in[1];
    const float* a   = (const float*)d_in[2];
    const int*   src = (const int*)d_in[3];
    const int*   dst = (const int*)d_in[4];
    float* out = (float*)d_out;

    const int n_nodes = in_sizes[0] / D_IN;   // 100000
    const int n_edges = in_sizes[3];          // 3200000

    auto align = [](size_t x) { return (x + 255) & ~(size_t)255; };
    char* w = (char*)d_ws;
    float* z  = (float*)w;                 w += align((size_t)n_nodes * D_OUT * sizeof(float));
    float* es = (float*)w;                 w += align((size_t)n_nodes * sizeof(float));
    float* ed = (float*)w;                 w += align((size_t)n_nodes * sizeof(float));
    unsigned int* count = (unsigned int*)w;  w += align((size_t)n_nodes * sizeof(unsigned int));
    unsigned int* off   = (unsigned int*)w;  w += align(((size_t)n_nodes + 1) * sizeof(unsigned int));
    unsigned int* blk_sums = (unsigned int*)w; w += align(256 * sizeof(unsigned int));
    unsigned int* blk_offs = (unsigned int*)w; w += align(256 * sizeof(unsigned int));
    int* ssrc = (int*)w;                   w += align((size_t)n_edges * sizeof(int));
    unsigned int* rank = (unsigned int*)w; // optional tail
    size_t need_rank = ((char*)rank - (char*)d_ws) + align((size_t)n_edges * sizeof(unsigned int));
    const bool use_rank = (ws_size >= need_rank);   // constant across calls: graph-safe

    hipMemsetAsync(count, 0, (size_t)n_nodes * sizeof(unsigned int), stream);

    // K1: projection — 8 nodes per wave, 4 waves per block
    {
        int waves = (n_nodes + NPW - 1) / NPW;
        k_project<<<(waves + 3) / 4, 256, 0, stream>>>(h, W, a, z, es, ed, n_nodes);
    }

    const int eblocks = (n_edges + 255) / 256;
    const int scan_blocks = (n_nodes + SCAN_ITEMS - 1) / SCAN_ITEMS;   // 49 for N=100k

    if (use_rank) {
        // single atomic pass: histogram + per-edge rank
        k_rank<<<eblocks, 256, 0, stream>>>(dst, count, rank, n_edges);
        k_scan1<<<scan_blocks, 256, 0, stream>>>(count, off, blk_sums, n_nodes);
        k_scan2<<<1, 256, 0, stream>>>(blk_sums, blk_offs, off, scan_blocks, n_nodes);
        k_scan3<<<(n_nodes + 255) / 256, 256, 0, stream>>>(off, count, blk_offs, n_nodes);
        // atomic-free placement
        k_place<<<eblocks, 256, 0, stream>>>(src, dst, off, rank, ssrc, n_edges);
    } else {
        // fallback: two atomic passes (round-2 scheme), cursor aliases count
        k_count<<<eblocks, 256, 0, stream>>>(dst, count, n_edges);
        k_scan1<<<scan_blocks, 256, 0, stream>>>(count, off, blk_sums, n_nodes);
        k_scan2<<<1, 256, 0, stream>>>(blk_sums, blk_offs, off, scan_blocks, n_nodes);
        k_scan3<<<(n_nodes + 255) / 256, 256, 0, stream>>>(off, count, blk_offs, n_nodes);
        k_fill<<<eblocks, 256, 0, stream>>>(src, dst, count, ssrc, n_edges);
    }

    // Fused softmax + gather: one wave per node, 4 nodes per block
    k_fused<<<(n_nodes + 3) / 4, 256, 0, stream>>>(ssrc, off, es, ed, z, out, n_nodes);
}

// Round 5
// 490.483 us; speedup vs baseline: 2.6465x; 1.1510x over previous
//
#include <hip/hip_runtime.h>

#define D_IN 128
#define D_OUT 64
#define SCAN_ITEMS 2048   // per scan block: 256 threads x 8 items
#define NPW 8             // nodes per wave in k_project

// fp32 -> bf16 (RNE) as ushort
__device__ __forceinline__ unsigned short f32_to_bf16(float f) {
    unsigned int u = __float_as_uint(f);
    u += 0x7fffu + ((u >> 16) & 1u);
    return (unsigned short)(u >> 16);
}

// ---------------------------------------------------------------------------
// K1: 8 nodes per wave, lane = output column. Writes z as bf16 and
// E[n] = exp(clamp(z[n]·a[:64])).  (ed term cancels in segment softmax.)
__global__ __launch_bounds__(256) void k_project(
    const float* __restrict__ h, const float* __restrict__ W,
    const float* __restrict__ a, unsigned short* __restrict__ z16,
    float* __restrict__ E, int n_nodes)
{
    int wave = (blockIdx.x * blockDim.x + threadIdx.x) >> 6;
    int lane = threadIdx.x & 63;
    int n0 = wave * NPW;
    if (n0 >= n_nodes) return;
    int nv = min(NPW, n_nodes - n0);   // valid nodes in this batch

    const float* hr[NPW];
#pragma unroll
    for (int n = 0; n < NPW; ++n)
        hr[n] = h + (size_t)(n0 + min(n, nv - 1)) * D_IN;

    float acc[NPW];
#pragma unroll
    for (int n = 0; n < NPW; ++n) acc[n] = 0.0f;

    for (int k4 = 0; k4 < D_IN / 4; ++k4) {
        float4 wk;                                   // W[k..k+3][lane], coalesced
        wk.x = W[(4 * k4 + 0) * D_OUT + lane];
        wk.y = W[(4 * k4 + 1) * D_OUT + lane];
        wk.z = W[(4 * k4 + 2) * D_OUT + lane];
        wk.w = W[(4 * k4 + 3) * D_OUT + lane];
#pragma unroll
        for (int n = 0; n < NPW; ++n) {
            const float4 hv = *(const float4*)(hr[n] + 4 * k4);  // wave-broadcast 16B
            acc[n] = fmaf(hv.x, wk.x, acc[n]);
            acc[n] = fmaf(hv.y, wk.y, acc[n]);
            acc[n] = fmaf(hv.z, wk.z, acc[n]);
            acc[n] = fmaf(hv.w, wk.w, acc[n]);
        }
    }

    float av = a[lane];
#pragma unroll
    for (int n = 0; n < NPW; ++n) {
        if (n < nv) z16[(size_t)(n0 + n) * D_OUT + lane] = f32_to_bf16(acc[n]);
        float pes = acc[n] * av;
#pragma unroll
        for (int o = 32; o > 0; o >>= 1)
            pes += __shfl_down(pes, o, 64);
        if (lane == 0 && n < nv)
            E[n0 + n] = __expf(fminf(fmaxf(pes, -60.0f), 60.0f));
    }
}

// ---------------------------------------------------------------------------
// Rank path: one atomic pass assigns per-edge rank within its dst segment
// AND builds the histogram. rank < 2^16 (max in-degree ~70 here).
__global__ __launch_bounds__(256) void k_rank(
    const int* __restrict__ dst, unsigned int* __restrict__ count,
    unsigned short* __restrict__ rank, int n_edges)
{
    int e = blockIdx.x * blockDim.x + threadIdx.x;
    if (e < n_edges) rank[e] = (unsigned short)atomicAdd(&count[dst[e]], 1u);
}

// Atomic-free placement: pos = off[dst] + rank.
__global__ __launch_bounds__(256) void k_place(
    const int* __restrict__ src, const int* __restrict__ dst,
    const unsigned int* __restrict__ off, const unsigned short* __restrict__ rank,
    int* __restrict__ ssrc, int n_edges)
{
    int e = blockIdx.x * blockDim.x + threadIdx.x;
    if (e < n_edges) ssrc[off[dst[e]] + (unsigned int)rank[e]] = src[e];
}

// Fallback path (small ws): histogram only.
__global__ __launch_bounds__(256) void k_count(
    const int* __restrict__ dst, unsigned int* __restrict__ count, int n_edges)
{
    int e = blockIdx.x * blockDim.x + threadIdx.x;
    if (e < n_edges) atomicAdd(&count[dst[e]], 1u);
}

// Fallback fill: atomic cursor.
__global__ __launch_bounds__(256) void k_fill(
    const int* __restrict__ src, const int* __restrict__ dst,
    unsigned int* __restrict__ cursor, int* __restrict__ ssrc, int n_edges)
{
    int e = blockIdx.x * blockDim.x + threadIdx.x;
    if (e < n_edges) {
        unsigned int pos = atomicAdd(&cursor[dst[e]], 1u);
        ssrc[pos] = src[e];
    }
}

// ---------------------------------------------------------------------------
// Exclusive scan, level 1.
__global__ __launch_bounds__(256) void k_scan1(
    const unsigned int* __restrict__ count, unsigned int* __restrict__ off,
    unsigned int* __restrict__ blk_sums, int n)
{
    __shared__ unsigned int tmp[256];
    int tid = threadIdx.x;
    int base = blockIdx.x * SCAN_ITEMS;
    unsigned int v[8]; unsigned int tsum = 0;
#pragma unroll
    for (int i = 0; i < 8; ++i) {
        int idx = base + tid * 8 + i;
        v[i] = (idx < n) ? count[idx] : 0u;
        tsum += v[i];
    }
    tmp[tid] = tsum; __syncthreads();
    for (int o = 1; o < 256; o <<= 1) {
        unsigned int u = (tid >= o) ? tmp[tid - o] : 0u; __syncthreads();
        tmp[tid] += u; __syncthreads();
    }
    unsigned int run = tmp[tid] - tsum;
    if (tid == 255) blk_sums[blockIdx.x] = tmp[255];
#pragma unroll
    for (int i = 0; i < 8; ++i) {
        int idx = base + tid * 8 + i;
        if (idx < n) off[idx] = run;
        run += v[i];
    }
}

// Level 2: single block scans the (<=256) block sums; writes off[n]=total.
__global__ __launch_bounds__(256) void k_scan2(
    const unsigned int* __restrict__ blk_sums, unsigned int* __restrict__ blk_offs,
    unsigned int* __restrict__ off, int nblocks, int n)
{
    __shared__ unsigned int tmp[256];
    int tid = threadIdx.x;
    unsigned int v = (tid < nblocks) ? blk_sums[tid] : 0u;
    tmp[tid] = v; __syncthreads();
    for (int o = 1; o < 256; o <<= 1) {
        unsigned int u = (tid >= o) ? tmp[tid - o] : 0u; __syncthreads();
        tmp[tid] += u; __syncthreads();
    }
    if (tid < nblocks) blk_offs[tid] = tmp[tid] - v;
    if (tid == 255) off[n] = tmp[255];
}

// Level 3: add block offsets; duplicate into cursor (consumed only by fallback).
__global__ __launch_bounds__(256) void k_scan3(
    unsigned int* __restrict__ off, unsigned int* __restrict__ cursor,
    const unsigned int* __restrict__ blk_offs, int n)
{
    int i = blockIdx.x * blockDim.x + threadIdx.x;
    if (i < n) {
        unsigned int o = off[i] + blk_offs[i / SCAN_ITEMS];
        off[i] = o; cursor[i] = o;
    }
}

// ---------------------------------------------------------------------------
// Fused weighted gather, SINGLE PASS (no max / no denom prepass):
//   out[d] = sum_e E[src_e] * z[src_e]  /  sum_e E[src_e]
// One wave per dst node; 8 edges in flight (8 lanes/edge, uint4 = 8 bf16/lane).
__global__ __launch_bounds__(256) void k_fused(
    const int* __restrict__ ssrc, const unsigned int* __restrict__ off,
    const float* __restrict__ E, const unsigned short* __restrict__ z16,
    float* __restrict__ out, int n_nodes)
{
    int node = (blockIdx.x * blockDim.x + threadIdx.x) >> 6;
    int lane = threadIdx.x & 63;
    if (node >= n_nodes) return;
    int g  = lane >> 3;   // edge group 0..7
    int fl = lane & 7;    // feature lane: features [8*fl, 8*fl+8)

    unsigned int start = off[node], end = off[node + 1];
    float* orow = out + (size_t)node * D_OUT;
    if (start == end) {   // no in-edges -> 0 (DGL)
        if (g == 0) {
            *(float4*)(orow + fl * 8)     = make_float4(0.f, 0.f, 0.f, 0.f);
            *(float4*)(orow + fl * 8 + 4) = make_float4(0.f, 0.f, 0.f, 0.f);
        }
        return;
    }

    float acc[8];
#pragma unroll
    for (int j = 0; j < 8; ++j) acc[j] = 0.0f;
    float wsum = 0.0f;

    for (unsigned int i = start + g; i < end; i += 8) {
        int sn = ssrc[i];          // group-broadcast 4B
        float w = E[sn];           // group-broadcast 4B gather (E is 400KB, cache-hot)
        wsum += w;
        // 16B = 8 bf16 features of this src row
        const uint4 p = *(const uint4*)(z16 + (size_t)sn * D_OUT + fl * 8);
        const unsigned int pu[4] = {p.x, p.y, p.z, p.w};
#pragma unroll
        for (int q = 0; q < 4; ++q) {
            float lo = __uint_as_float(pu[q] << 16);
            float hi = __uint_as_float(pu[q] & 0xffff0000u);
            acc[2 * q]     = fmaf(w, lo, acc[2 * q]);
            acc[2 * q + 1] = fmaf(w, hi, acc[2 * q + 1]);
        }
    }

    // reduce the 8 edge-groups (xor over the g bits: 8,16,32)
#pragma unroll
    for (int o = 8; o <= 32; o <<= 1) {
#pragma unroll
        for (int j = 0; j < 8; ++j) acc[j] += __shfl_xor(acc[j], o, 64);
        wsum += __shfl_xor(wsum, o, 64);
    }

    if (g == 0) {
        float inv = 1.0f / wsum;
        float4 o0 = make_float4(acc[0] * inv, acc[1] * inv, acc[2] * inv, acc[3] * inv);
        float4 o1 = make_float4(acc[4] * inv, acc[5] * inv, acc[6] * inv, acc[7] * inv);
        *(float4*)(orow + fl * 8)     = o0;
        *(float4*)(orow + fl * 8 + 4) = o1;
    }
}

// ---------------------------------------------------------------------------
extern "C" void kernel_launch(void* const* d_in, const int* in_sizes, int n_in,
                              void* d_out, int out_size, void* d_ws, size_t ws_size,
                              hipStream_t stream) {
    const float* h   = (const float*)d_in[0];
    const float* W   = (const float*)d_in[1];
    const float* a   = (const float*)d_in[2];
    const int*   src = (const int*)d_in[3];
    const int*   dst = (const int*)d_in[4];
    float* out = (float*)d_out;

    const int n_nodes = in_sizes[0] / D_IN;   // 100000
    const int n_edges = in_sizes[3];          // 3200000

    auto align = [](size_t x) { return (x + 255) & ~(size_t)255; };
    char* w = (char*)d_ws;
    unsigned short* z16 = (unsigned short*)w;  w += align((size_t)n_nodes * D_OUT * sizeof(unsigned short));
    float* E = (float*)w;                      w += align((size_t)n_nodes * sizeof(float));
    unsigned int* count = (unsigned int*)w;    w += align((size_t)n_nodes * sizeof(unsigned int));
    unsigned int* off   = (unsigned int*)w;    w += align(((size_t)n_nodes + 1) * sizeof(unsigned int));
    unsigned int* blk_sums = (unsigned int*)w; w += align(256 * sizeof(unsigned int));
    unsigned int* blk_offs = (unsigned int*)w; w += align(256 * sizeof(unsigned int));
    int* ssrc = (int*)w;                       w += align((size_t)n_edges * sizeof(int));
    unsigned short* rank = (unsigned short*)w; // optional tail
    size_t need_rank = ((char*)rank - (char*)d_ws) + align((size_t)n_edges * sizeof(unsigned short));
    const bool use_rank = (ws_size >= need_rank);   // constant across calls: graph-safe

    hipMemsetAsync(count, 0, (size_t)n_nodes * sizeof(unsigned int), stream);

    // K1: projection — 8 nodes per wave, 4 waves per block
    {
        int waves = (n_nodes + NPW - 1) / NPW;
        k_project<<<(waves + 3) / 4, 256, 0, stream>>>(h, W, a, z16, E, n_nodes);
    }

    const int eblocks = (n_edges + 255) / 256;
    const int scan_blocks = (n_nodes + SCAN_ITEMS - 1) / SCAN_ITEMS;   // 49 for N=100k

    if (use_rank) {
        k_rank<<<eblocks, 256, 0, stream>>>(dst, count, rank, n_edges);
        k_scan1<<<scan_blocks, 256, 0, stream>>>(count, off, blk_sums, n_nodes);
        k_scan2<<<1, 256, 0, stream>>>(blk_sums, blk_offs, off, scan_blocks, n_nodes);
        k_scan3<<<(n_nodes + 255) / 256, 256, 0, stream>>>(off, count, blk_offs, n_nodes);
        k_place<<<eblocks, 256, 0, stream>>>(src, dst, off, rank, ssrc, n_edges);
    } else {
        k_count<<<eblocks, 256, 0, stream>>>(dst, count, n_edges);
        k_scan1<<<scan_blocks, 256, 0, stream>>>(count, off, blk_sums, n_nodes);
        k_scan2<<<1, 256, 0, stream>>>(blk_sums, blk_offs, off, scan_blocks, n_nodes);
        k_scan3<<<(n_nodes + 255) / 256, 256, 0, stream>>>(off, count, blk_offs, n_nodes);
        k_fill<<<eblocks, 256, 0, stream>>>(src, dst, count, ssrc, n_edges);
    }

    // Fused single-pass softmax-weighted gather: one wave per node
    k_fused<<<(n_nodes + 3) / 4, 256, 0, stream>>>(ssrc, off, E, z16, out, n_nodes);
}

// Round 6
// 384.840 us; speedup vs baseline: 3.3730x; 1.2745x over previous
//
#include <hip/hip_runtime.h>

#define D_IN 128
#define D_OUT 64
#define SCAN_ITEMS 2048   // per scan block: 256 threads x 8 items
#define NPW 8             // nodes per wave in k_project
#define TILE 4096         // edges per partition tile
#define BSHIFT 8          // coarse bucket = dst >> 8 (256 dst per bucket)
#define MAXNB 512         // max coarse buckets supported by LDS arrays

// fp32 -> bf16 (RNE) as ushort
__device__ __forceinline__ unsigned short f32_to_bf16(float f) {
    unsigned int u = __float_as_uint(f);
    u += 0x7fffu + ((u >> 16) & 1u);
    return (unsigned short)(u >> 16);
}

// ---------------------------------------------------------------------------
// K1: 8 nodes per wave, lane = output column. Writes z as bf16 and
// E[n] = exp(clamp(z[n]·a[:64])).  (ed term cancels in segment softmax.)
__global__ __launch_bounds__(256) void k_project(
    const float* __restrict__ h, const float* __restrict__ W,
    const float* __restrict__ a, unsigned short* __restrict__ z16,
    float* __restrict__ E, int n_nodes)
{
    int wave = (blockIdx.x * blockDim.x + threadIdx.x) >> 6;
    int lane = threadIdx.x & 63;
    int n0 = wave * NPW;
    if (n0 >= n_nodes) return;
    int nv = min(NPW, n_nodes - n0);

    const float* hr[NPW];
#pragma unroll
    for (int n = 0; n < NPW; ++n)
        hr[n] = h + (size_t)(n0 + min(n, nv - 1)) * D_IN;

    float acc[NPW];
#pragma unroll
    for (int n = 0; n < NPW; ++n) acc[n] = 0.0f;

    for (int k4 = 0; k4 < D_IN / 4; ++k4) {
        float4 wk;                                   // W[k..k+3][lane], coalesced
        wk.x = W[(4 * k4 + 0) * D_OUT + lane];
        wk.y = W[(4 * k4 + 1) * D_OUT + lane];
        wk.z = W[(4 * k4 + 2) * D_OUT + lane];
        wk.w = W[(4 * k4 + 3) * D_OUT + lane];
#pragma unroll
        for (int n = 0; n < NPW; ++n) {
            const float4 hv = *(const float4*)(hr[n] + 4 * k4);  // wave-broadcast 16B
            acc[n] = fmaf(hv.x, wk.x, acc[n]);
            acc[n] = fmaf(hv.y, wk.y, acc[n]);
            acc[n] = fmaf(hv.z, wk.z, acc[n]);
            acc[n] = fmaf(hv.w, wk.w, acc[n]);
        }
    }

    float av = a[lane];
#pragma unroll
    for (int n = 0; n < NPW; ++n) {
        if (n < nv) z16[(size_t)(n0 + n) * D_OUT + lane] = f32_to_bf16(acc[n]);
        float pes = acc[n] * av;
#pragma unroll
        for (int o = 32; o > 0; o >>= 1)
            pes += __shfl_down(pes, o, 64);
        if (lane == 0 && n < nv)
            E[n0 + n] = __expf(fminf(fmaxf(pes, -60.0f), 60.0f));
    }
}

// ---------------------------------------------------------------------------
// Counting-sort phase A: per-tile LDS histogram of coarse buckets.
// histT[b * NT + t] = #edges of tile t in bucket b (bucket-major for the scan).
__global__ __launch_bounds__(256) void k_hist(
    const int* __restrict__ dst, unsigned int* __restrict__ histT,
    int n_edges, int NB, int NT)
{
    __shared__ unsigned int hcnt[MAXNB];
    int t = blockIdx.x;
    for (int b = threadIdx.x; b < NB; b += 256) hcnt[b] = 0;
    __syncthreads();
    int base = t * TILE;
    int lim = min(base + TILE, n_edges);
    for (int i = base + threadIdx.x; i < lim; i += 256)
        atomicAdd(&hcnt[(unsigned int)dst[i] >> BSHIFT], 1u);
    __syncthreads();
    for (int b = threadIdx.x; b < NB; b += 256)
        histT[(size_t)b * NT + t] = hcnt[b];
}

// Phase A2: scatter packed (src<<8 | dst&255) into bucket-grouped tmp using
// LDS cursors seeded from the scanned histT. Writes are contiguous runs per
// (bucket, tile) -> cachelines fill within the block's lifetime.
__global__ __launch_bounds__(256) void k_partition(
    const int* __restrict__ src, const int* __restrict__ dst,
    const unsigned int* __restrict__ histT, unsigned int* __restrict__ tmp,
    int n_edges, int NB, int NT)
{
    __shared__ unsigned int cur[MAXNB];
    int t = blockIdx.x;
    for (int b = threadIdx.x; b < NB; b += 256)
        cur[b] = histT[(size_t)b * NT + t];
    __syncthreads();
    int base = t * TILE;
    int lim = min(base + TILE, n_edges);
    for (int i = base + threadIdx.x; i < lim; i += 256) {
        unsigned int d = (unsigned int)dst[i];
        unsigned int pos = atomicAdd(&cur[d >> BSHIFT], 1u);
        tmp[pos] = ((unsigned int)src[i] << BSHIFT) | (d & ((1u << BSHIFT) - 1u));
    }
}

// Phase B: one block per bucket. 256 local bins: LDS histogram + LDS scan ->
// off[] (coalesced) and final ssrc placement via LDS cursors (33KB window).
__global__ __launch_bounds__(256) void k_bucket(
    const unsigned int* __restrict__ tmp, const unsigned int* __restrict__ histT,
    unsigned int* __restrict__ off, int* __restrict__ ssrc,
    int n_edges, int n_nodes, int NB, int NT)
{
    __shared__ unsigned int cnt[256];
    __shared__ unsigned int sc[256];
    int b = blockIdx.x;
    int tid = threadIdx.x;
    unsigned int s0 = histT[(size_t)b * NT];
    unsigned int s1 = (b + 1 < NB) ? histT[(size_t)(b + 1) * NT] : (unsigned int)n_edges;

    cnt[tid] = 0;
    __syncthreads();
    for (unsigned int i = s0 + tid; i < s1; i += 256)
        atomicAdd(&cnt[tmp[i] & 255u], 1u);
    __syncthreads();

    unsigned int myc = cnt[tid];
    sc[tid] = myc;
    __syncthreads();
    for (int o = 1; o < 256; o <<= 1) {
        unsigned int u = (tid >= o) ? sc[tid - o] : 0u;
        __syncthreads();
        sc[tid] += u;
        __syncthreads();
    }
    unsigned int excl = sc[tid] - myc;

    int d = (b << BSHIFT) + tid;
    if (d < n_nodes) off[d] = s0 + excl;
    if (b == 0 && tid == 0) off[n_nodes] = (unsigned int)n_edges;

    cnt[tid] = excl;   // reuse as cursor (all prior cnt reads completed)
    __syncthreads();
    for (unsigned int i = s0 + tid; i < s1; i += 256) {
        unsigned int v = tmp[i];
        unsigned int pos = s0 + atomicAdd(&cnt[v & 255u], 1u);
        ssrc[pos] = (int)(v >> BSHIFT);
    }
}

// ---------------------------------------------------------------------------
// Fallback kernels (small ws): atomic rank / fill paths from round 5.
__global__ __launch_bounds__(256) void k_rank(
    const int* __restrict__ dst, unsigned int* __restrict__ count,
    unsigned short* __restrict__ rank, int n_edges)
{
    int e = blockIdx.x * blockDim.x + threadIdx.x;
    if (e < n_edges) rank[e] = (unsigned short)atomicAdd(&count[dst[e]], 1u);
}

__global__ __launch_bounds__(256) void k_place(
    const int* __restrict__ src, const int* __restrict__ dst,
    const unsigned int* __restrict__ off, const unsigned short* __restrict__ rank,
    int* __restrict__ ssrc, int n_edges)
{
    int e = blockIdx.x * blockDim.x + threadIdx.x;
    if (e < n_edges) ssrc[off[dst[e]] + (unsigned int)rank[e]] = src[e];
}

__global__ __launch_bounds__(256) void k_count(
    const int* __restrict__ dst, unsigned int* __restrict__ count, int n_edges)
{
    int e = blockIdx.x * blockDim.x + threadIdx.x;
    if (e < n_edges) atomicAdd(&count[dst[e]], 1u);
}

__global__ __launch_bounds__(256) void k_fill(
    const int* __restrict__ src, const int* __restrict__ dst,
    unsigned int* __restrict__ cursor, int* __restrict__ ssrc, int n_edges)
{
    int e = blockIdx.x * blockDim.x + threadIdx.x;
    if (e < n_edges) {
        unsigned int pos = atomicAdd(&cursor[dst[e]], 1u);
        ssrc[pos] = src[e];
    }
}

// ---------------------------------------------------------------------------
// Exclusive scan (3 levels). scan1 is safe in-place (count==off).
__global__ __launch_bounds__(256) void k_scan1(
    const unsigned int* __restrict__ count, unsigned int* __restrict__ off,
    unsigned int* __restrict__ blk_sums, int n)
{
    __shared__ unsigned int tmp[256];
    int tid = threadIdx.x;
    int base = blockIdx.x * SCAN_ITEMS;
    unsigned int v[8]; unsigned int tsum = 0;
#pragma unroll
    for (int i = 0; i < 8; ++i) {
        int idx = base + tid * 8 + i;
        v[i] = (idx < n) ? count[idx] : 0u;
        tsum += v[i];
    }
    tmp[tid] = tsum; __syncthreads();
    for (int o = 1; o < 256; o <<= 1) {
        unsigned int u = (tid >= o) ? tmp[tid - o] : 0u; __syncthreads();
        tmp[tid] += u; __syncthreads();
    }
    unsigned int run = tmp[tid] - tsum;
    if (tid == 255) blk_sums[blockIdx.x] = tmp[255];
#pragma unroll
    for (int i = 0; i < 8; ++i) {
        int idx = base + tid * 8 + i;
        if (idx < n) off[idx] = run;
        run += v[i];
    }
}

__global__ __launch_bounds__(256) void k_scan2(
    const unsigned int* __restrict__ blk_sums, unsigned int* __restrict__ blk_offs,
    unsigned int* __restrict__ off, int nblocks, int n)
{
    __shared__ unsigned int tmp[256];
    int tid = threadIdx.x;
    unsigned int v = (tid < nblocks) ? blk_sums[tid] : 0u;
    tmp[tid] = v; __syncthreads();
    for (int o = 1; o < 256; o <<= 1) {
        unsigned int u = (tid >= o) ? tmp[tid - o] : 0u; __syncthreads();
        tmp[tid] += u; __syncthreads();
    }
    if (tid < nblocks) blk_offs[tid] = tmp[tid] - v;
    if (tid == 255) off[n] = tmp[255];
}

__global__ __launch_bounds__(256) void k_scan3(
    unsigned int* __restrict__ off, unsigned int* __restrict__ cursor,
    const unsigned int* __restrict__ blk_offs, int n)
{
    int i = blockIdx.x * blockDim.x + threadIdx.x;
    if (i < n) {
        unsigned int o = off[i] + blk_offs[i / SCAN_ITEMS];
        off[i] = o; cursor[i] = o;
    }
}

// ---------------------------------------------------------------------------
// Fused weighted gather, single pass:
//   out[d] = sum_e E[src_e] * z[src_e]  /  sum_e E[src_e]
// One wave per dst node; 8 edges in flight (8 lanes/edge, uint4 = 8 bf16/lane).
__global__ __launch_bounds__(256) void k_fused(
    const int* __restrict__ ssrc, const unsigned int* __restrict__ off,
    const float* __restrict__ E, const unsigned short* __restrict__ z16,
    float* __restrict__ out, int n_nodes)
{
    int node = (blockIdx.x * blockDim.x + threadIdx.x) >> 6;
    int lane = threadIdx.x & 63;
    if (node >= n_nodes) return;
    int g  = lane >> 3;   // edge group 0..7
    int fl = lane & 7;    // feature lane: features [8*fl, 8*fl+8)

    unsigned int start = off[node], end = off[node + 1];
    float* orow = out + (size_t)node * D_OUT;
    if (start == end) {   // no in-edges -> 0 (DGL)
        if (g == 0) {
            *(float4*)(orow + fl * 8)     = make_float4(0.f, 0.f, 0.f, 0.f);
            *(float4*)(orow + fl * 8 + 4) = make_float4(0.f, 0.f, 0.f, 0.f);
        }
        return;
    }

    float acc[8];
#pragma unroll
    for (int j = 0; j < 8; ++j) acc[j] = 0.0f;
    float wsum = 0.0f;

    for (unsigned int i = start + g; i < end; i += 8) {
        int sn = ssrc[i];
        float w = E[sn];
        wsum += w;
        const uint4 p = *(const uint4*)(z16 + (size_t)sn * D_OUT + fl * 8);
        const unsigned int pu[4] = {p.x, p.y, p.z, p.w};
#pragma unroll
        for (int q = 0; q < 4; ++q) {
            float lo = __uint_as_float(pu[q] << 16);
            float hi = __uint_as_float(pu[q] & 0xffff0000u);
            acc[2 * q]     = fmaf(w, lo, acc[2 * q]);
            acc[2 * q + 1] = fmaf(w, hi, acc[2 * q + 1]);
        }
    }

#pragma unroll
    for (int o = 8; o <= 32; o <<= 1) {
#pragma unroll
        for (int j = 0; j < 8; ++j) acc[j] += __shfl_xor(acc[j], o, 64);
        wsum += __shfl_xor(wsum, o, 64);
    }

    if (g == 0) {
        float inv = 1.0f / wsum;
        float4 o0 = make_float4(acc[0] * inv, acc[1] * inv, acc[2] * inv, acc[3] * inv);
        float4 o1 = make_float4(acc[4] * inv, acc[5] * inv, acc[6] * inv, acc[7] * inv);
        *(float4*)(orow + fl * 8)     = o0;
        *(float4*)(orow + fl * 8 + 4) = o1;
    }
}

// ---------------------------------------------------------------------------
extern "C" void kernel_launch(void* const* d_in, const int* in_sizes, int n_in,
                              void* d_out, int out_size, void* d_ws, size_t ws_size,
                              hipStream_t stream) {
    const float* h   = (const float*)d_in[0];
    const float* W   = (const float*)d_in[1];
    const float* a   = (const float*)d_in[2];
    const int*   src = (const int*)d_in[3];
    const int*   dst = (const int*)d_in[4];
    float* out = (float*)d_out;

    const int n_nodes = in_sizes[0] / D_IN;   // 100000
    const int n_edges = in_sizes[3];          // 3200000

    const int NB = (n_nodes + (1 << BSHIFT) - 1) >> BSHIFT;   // 391
    const int NT = (n_edges + TILE - 1) / TILE;               // 782
    const size_t histT_elems = (size_t)NB * NT + 1;           // +1 for scan total
    const int n_scan = NB * NT;
    const int sb_sort = (n_scan + SCAN_ITEMS - 1) / SCAN_ITEMS;   // 150

    auto align = [](size_t x) { return (x + 255) & ~(size_t)255; };
    char* w = (char*)d_ws;
    unsigned short* z16 = (unsigned short*)w;  w += align((size_t)n_nodes * D_OUT * sizeof(unsigned short));
    float* E = (float*)w;                      w += align((size_t)n_nodes * sizeof(float));
    unsigned int* off = (unsigned int*)w;      w += align(((size_t)n_nodes + 1) * sizeof(unsigned int));
    unsigned int* blk_sums = (unsigned int*)w; w += align(256 * sizeof(unsigned int));
    unsigned int* blk_offs = (unsigned int*)w; w += align(256 * sizeof(unsigned int));
    // region shared by histT (sort path) and count (fallback paths)
    size_t hist_region = align(((histT_elems > (size_t)n_nodes ? histT_elems : (size_t)n_nodes)) * sizeof(unsigned int));
    unsigned int* histT = (unsigned int*)w;    w += hist_region;
    unsigned int* count = histT;
    int* ssrc = (int*)w;                       w += align((size_t)n_edges * sizeof(int));
    // region shared by tmp (sort path) and rank (rank fallback)
    unsigned int* tmp = (unsigned int*)w;
    unsigned short* rank = (unsigned short*)tmp;
    size_t need_sort = ((char*)tmp - (char*)d_ws) + align((size_t)n_edges * sizeof(unsigned int));
    size_t need_rank = ((char*)tmp - (char*)d_ws) + align((size_t)n_edges * sizeof(unsigned short));
    size_t need_fill = (char*)tmp - (char*)d_ws;

    const bool use_sort = (ws_size >= need_sort) && NB <= MAXNB &&
                          n_nodes < (1 << 24) && sb_sort <= 256;
    const bool use_rank = !use_sort && (ws_size >= need_rank);
    (void)need_fill;

    // K1: projection — 8 nodes per wave, 4 waves per block
    {
        int waves = (n_nodes + NPW - 1) / NPW;
        k_project<<<(waves + 3) / 4, 256, 0, stream>>>(h, W, a, z16, E, n_nodes);
    }

    const int eblocks = (n_edges + 255) / 256;
    const int sb_node = (n_nodes + SCAN_ITEMS - 1) / SCAN_ITEMS;   // 49

    if (use_sort) {
        // atomic-free two-level counting sort
        k_hist<<<NT, 256, 0, stream>>>(dst, histT, n_edges, NB, NT);
        k_scan1<<<sb_sort, 256, 0, stream>>>(histT, histT, blk_sums, n_scan);
        k_scan2<<<1, 256, 0, stream>>>(blk_sums, blk_offs, histT, sb_sort, n_scan);
        k_scan3<<<(n_scan + 255) / 256, 256, 0, stream>>>(histT, histT, blk_offs, n_scan);
        k_partition<<<NT, 256, 0, stream>>>(src, dst, histT, tmp, n_edges, NB, NT);
        k_bucket<<<NB, 256, 0, stream>>>(tmp, histT, off, ssrc, n_edges, n_nodes, NB, NT);
    } else if (use_rank) {
        hipMemsetAsync(count, 0, (size_t)n_nodes * sizeof(unsigned int), stream);
        k_rank<<<eblocks, 256, 0, stream>>>(dst, count, rank, n_edges);
        k_scan1<<<sb_node, 256, 0, stream>>>(count, off, blk_sums, n_nodes);
        k_scan2<<<1, 256, 0, stream>>>(blk_sums, blk_offs, off, sb_node, n_nodes);
        k_scan3<<<(n_nodes + 255) / 256, 256, 0, stream>>>(off, count, blk_offs, n_nodes);
        k_place<<<eblocks, 256, 0, stream>>>(src, dst, off, rank, ssrc, n_edges);
    } else {
        hipMemsetAsync(count, 0, (size_t)n_nodes * sizeof(unsigned int), stream);
        k_count<<<eblocks, 256, 0, stream>>>(dst, count, n_edges);
        k_scan1<<<sb_node, 256, 0, stream>>>(count, off, blk_sums, n_nodes);
        k_scan2<<<1, 256, 0, stream>>>(blk_sums, blk_offs, off, sb_node, n_nodes);
        k_scan3<<<(n_nodes + 255) / 256, 256, 0, stream>>>(off, count, blk_offs, n_nodes);
        k_fill<<<eblocks, 256, 0, stream>>>(src, dst, count, ssrc, n_edges);
    }

    // Fused single-pass softmax-weighted gather: one wave per node
    k_fused<<<(n_nodes + 3) / 4, 256, 0, stream>>>(ssrc, off, E, z16, out, n_nodes);
}

// Round 7
// 306.170 us; speedup vs baseline: 4.2397x; 1.2569x over previous
//
#include <hip/hip_runtime.h>

#define D_IN 128
#define D_OUT 64
#define SCAN_ITEMS 2048   // per scan block: 256 threads x 8 items
#define TILE 4096         // edges per partition tile
#define BSHIFT 8          // coarse bucket = dst >> 8 (256 dst per bucket)
#define MAXNB 512         // max coarse buckets supported by LDS arrays
#define BN 64             // nodes per block in k_project
#define HS_STRIDE 132     // 128 + 4 pad: 4*132 mod 32 = 16 -> 2-way (free), not 4-way

// fp32 -> bf16 (RNE) as ushort
__device__ __forceinline__ unsigned short f32_to_bf16(float f) {
    unsigned int u = __float_as_uint(f);
    u += 0x7fffu + ((u >> 16) & 1u);
    return (unsigned short)(u >> 16);
}

// ---------------------------------------------------------------------------
// K1: LDS-tiled projection GEMM. Block = 256 threads = 64 nodes.
// Stage h-tile (64x128, coalesced float4) + all of W (128x64) into LDS;
// each thread computes a 4-node x 4-col register tile (64 FMAs per 8 LDS b128).
// Epilogue: es = z·a[:64] reduced over 16-lane groups; E = exp(clamp(es)).
__global__ __launch_bounds__(256) void k_project(
    const float* __restrict__ h, const float* __restrict__ W,
    const float* __restrict__ a, unsigned short* __restrict__ z16,
    float* __restrict__ E, int n_nodes)
{
    __shared__ float ws[D_IN * D_OUT];      // [k][col], 32 KB
    __shared__ float hs[BN * HS_STRIDE];    // [node][k], 33.8 KB

    const int tid = threadIdx.x;
    const int nbase = blockIdx.x * BN;

    // stage W: 8192 floats = 2048 float4, coalesced
#pragma unroll
    for (int i = 0; i < 8; ++i) {
        int f = (tid + 256 * i) * 4;
        *(float4*)&ws[f] = *(const float4*)&W[f];
    }
    // stage h tile: 2048 float4, coalesced (1 KB per wave-instruction)
#pragma unroll
    for (int j = 0; j < 8; ++j) {
        int f = tid + 256 * j;              // float4 index
        int row = f >> 5;                   // 32 float4 per row
        int kk = (f & 31) << 2;
        int gr = nbase + row;
        float4 v = make_float4(0.f, 0.f, 0.f, 0.f);
        if (gr < n_nodes) v = *(const float4*)&h[(size_t)gr * D_IN + kk];
        *(float4*)&hs[row * HS_STRIDE + kk] = v;
    }
    __syncthreads();

    // thread tile: cols [c4, c4+4), local nodes [n4, n4+4)
    const int c4 = (tid & 15) * 4;
    const int n4 = (tid >> 4) * 4;

    float acc[4][4];
#pragma unroll
    for (int i = 0; i < 4; ++i)
#pragma unroll
        for (int j = 0; j < 4; ++j) acc[i][j] = 0.0f;

    for (int k = 0; k < D_IN; k += 4) {
        float4 wv0 = *(float4*)&ws[(k + 0) * D_OUT + c4];
        float4 wv1 = *(float4*)&ws[(k + 1) * D_OUT + c4];
        float4 wv2 = *(float4*)&ws[(k + 2) * D_OUT + c4];
        float4 wv3 = *(float4*)&ws[(k + 3) * D_OUT + c4];
#pragma unroll
        for (int i = 0; i < 4; ++i) {
            float4 hv = *(float4*)&hs[(n4 + i) * HS_STRIDE + k];
            acc[i][0] = fmaf(hv.x, wv0.x, acc[i][0]);
            acc[i][1] = fmaf(hv.x, wv0.y, acc[i][1]);
            acc[i][2] = fmaf(hv.x, wv0.z, acc[i][2]);
            acc[i][3] = fmaf(hv.x, wv0.w, acc[i][3]);
            acc[i][0] = fmaf(hv.y, wv1.x, acc[i][0]);
            acc[i][1] = fmaf(hv.y, wv1.y, acc[i][1]);
            acc[i][2] = fmaf(hv.y, wv1.z, acc[i][2]);
            acc[i][3] = fmaf(hv.y, wv1.w, acc[i][3]);
            acc[i][0] = fmaf(hv.z, wv2.x, acc[i][0]);
            acc[i][1] = fmaf(hv.z, wv2.y, acc[i][1]);
            acc[i][2] = fmaf(hv.z, wv2.z, acc[i][2]);
            acc[i][3] = fmaf(hv.z, wv2.w, acc[i][3]);
            acc[i][0] = fmaf(hv.w, wv3.x, acc[i][0]);
            acc[i][1] = fmaf(hv.w, wv3.y, acc[i][1]);
            acc[i][2] = fmaf(hv.w, wv3.z, acc[i][2]);
            acc[i][3] = fmaf(hv.w, wv3.w, acc[i][3]);
        }
    }

    // epilogue: z16 write + es reduction
    float a0 = a[c4 + 0], a1 = a[c4 + 1], a2 = a[c4 + 2], a3 = a[c4 + 3];
#pragma unroll
    for (int i = 0; i < 4; ++i) {
        int node = nbase + n4 + i;
        bool ok = node < n_nodes;
        if (ok) {
            ushort4 q;
            q.x = f32_to_bf16(acc[i][0]);
            q.y = f32_to_bf16(acc[i][1]);
            q.z = f32_to_bf16(acc[i][2]);
            q.w = f32_to_bf16(acc[i][3]);
            *(ushort4*)&z16[(size_t)node * D_OUT + c4] = q;
        }
        float es_p = acc[i][0] * a0 + acc[i][1] * a1 + acc[i][2] * a2 + acc[i][3] * a3;
        // reduce across the 16 lanes sharing this node (lane bits 0..3)
        es_p += __shfl_xor(es_p, 1, 64);
        es_p += __shfl_xor(es_p, 2, 64);
        es_p += __shfl_xor(es_p, 4, 64);
        es_p += __shfl_xor(es_p, 8, 64);
        if ((tid & 15) == 0 && ok)
            E[node] = __expf(fminf(fmaxf(es_p, -60.0f), 60.0f));
    }
}

// ---------------------------------------------------------------------------
// Counting-sort phase A: per-tile LDS histogram of coarse buckets.
__global__ __launch_bounds__(256) void k_hist(
    const int* __restrict__ dst, unsigned int* __restrict__ histT,
    int n_edges, int NB, int NT)
{
    __shared__ unsigned int hcnt[MAXNB];
    int t = blockIdx.x;
    for (int b = threadIdx.x; b < NB; b += 256) hcnt[b] = 0;
    __syncthreads();
    int base = t * TILE;
    int lim = min(base + TILE, n_edges);
    for (int i = base + threadIdx.x; i < lim; i += 256)
        atomicAdd(&hcnt[(unsigned int)dst[i] >> BSHIFT], 1u);
    __syncthreads();
    for (int b = threadIdx.x; b < NB; b += 256)
        histT[(size_t)b * NT + t] = hcnt[b];
}

// Phase A2: scatter packed (src<<8 | dst&255) into bucket-grouped tmp.
__global__ __launch_bounds__(256) void k_partition(
    const int* __restrict__ src, const int* __restrict__ dst,
    const unsigned int* __restrict__ histT, unsigned int* __restrict__ tmp,
    int n_edges, int NB, int NT)
{
    __shared__ unsigned int cur[MAXNB];
    int t = blockIdx.x;
    for (int b = threadIdx.x; b < NB; b += 256)
        cur[b] = histT[(size_t)b * NT + t];
    __syncthreads();
    int base = t * TILE;
    int lim = min(base + TILE, n_edges);
    for (int i = base + threadIdx.x; i < lim; i += 256) {
        unsigned int d = (unsigned int)dst[i];
        unsigned int pos = atomicAdd(&cur[d >> BSHIFT], 1u);
        tmp[pos] = ((unsigned int)src[i] << BSHIFT) | (d & ((1u << BSHIFT) - 1u));
    }
}

// Phase B: one block per bucket -> off[] + final ssrc placement.
__global__ __launch_bounds__(256) void k_bucket(
    const unsigned int* __restrict__ tmp, const unsigned int* __restrict__ histT,
    unsigned int* __restrict__ off, int* __restrict__ ssrc,
    int n_edges, int n_nodes, int NB, int NT)
{
    __shared__ unsigned int cnt[256];
    __shared__ unsigned int sc[256];
    int b = blockIdx.x;
    int tid = threadIdx.x;
    unsigned int s0 = histT[(size_t)b * NT];
    unsigned int s1 = (b + 1 < NB) ? histT[(size_t)(b + 1) * NT] : (unsigned int)n_edges;

    cnt[tid] = 0;
    __syncthreads();
    for (unsigned int i = s0 + tid; i < s1; i += 256)
        atomicAdd(&cnt[tmp[i] & 255u], 1u);
    __syncthreads();

    unsigned int myc = cnt[tid];
    sc[tid] = myc;
    __syncthreads();
    for (int o = 1; o < 256; o <<= 1) {
        unsigned int u = (tid >= o) ? sc[tid - o] : 0u;
        __syncthreads();
        sc[tid] += u;
        __syncthreads();
    }
    unsigned int excl = sc[tid] - myc;

    int d = (b << BSHIFT) + tid;
    if (d < n_nodes) off[d] = s0 + excl;
    if (b == 0 && tid == 0) off[n_nodes] = (unsigned int)n_edges;

    cnt[tid] = excl;   // reuse as cursor
    __syncthreads();
    for (unsigned int i = s0 + tid; i < s1; i += 256) {
        unsigned int v = tmp[i];
        unsigned int pos = s0 + atomicAdd(&cnt[v & 255u], 1u);
        ssrc[pos] = (int)(v >> BSHIFT);
    }
}

// ---------------------------------------------------------------------------
// Fallback kernels (small ws): atomic rank / fill paths.
__global__ __launch_bounds__(256) void k_rank(
    const int* __restrict__ dst, unsigned int* __restrict__ count,
    unsigned short* __restrict__ rank, int n_edges)
{
    int e = blockIdx.x * blockDim.x + threadIdx.x;
    if (e < n_edges) rank[e] = (unsigned short)atomicAdd(&count[dst[e]], 1u);
}

__global__ __launch_bounds__(256) void k_place(
    const int* __restrict__ src, const int* __restrict__ dst,
    const unsigned int* __restrict__ off, const unsigned short* __restrict__ rank,
    int* __restrict__ ssrc, int n_edges)
{
    int e = blockIdx.x * blockDim.x + threadIdx.x;
    if (e < n_edges) ssrc[off[dst[e]] + (unsigned int)rank[e]] = src[e];
}

__global__ __launch_bounds__(256) void k_count(
    const int* __restrict__ dst, unsigned int* __restrict__ count, int n_edges)
{
    int e = blockIdx.x * blockDim.x + threadIdx.x;
    if (e < n_edges) atomicAdd(&count[dst[e]], 1u);
}

__global__ __launch_bounds__(256) void k_fill(
    const int* __restrict__ src, const int* __restrict__ dst,
    unsigned int* __restrict__ cursor, int* __restrict__ ssrc, int n_edges)
{
    int e = blockIdx.x * blockDim.x + threadIdx.x;
    if (e < n_edges) {
        unsigned int pos = atomicAdd(&cursor[dst[e]], 1u);
        ssrc[pos] = src[e];
    }
}

// ---------------------------------------------------------------------------
// Exclusive scan (3 levels). scan1 is safe in-place (count==off).
__global__ __launch_bounds__(256) void k_scan1(
    const unsigned int* __restrict__ count, unsigned int* __restrict__ off,
    unsigned int* __restrict__ blk_sums, int n)
{
    __shared__ unsigned int tmp[256];
    int tid = threadIdx.x;
    int base = blockIdx.x * SCAN_ITEMS;
    unsigned int v[8]; unsigned int tsum = 0;
#pragma unroll
    for (int i = 0; i < 8; ++i) {
        int idx = base + tid * 8 + i;
        v[i] = (idx < n) ? count[idx] : 0u;
        tsum += v[i];
    }
    tmp[tid] = tsum; __syncthreads();
    for (int o = 1; o < 256; o <<= 1) {
        unsigned int u = (tid >= o) ? tmp[tid - o] : 0u; __syncthreads();
        tmp[tid] += u; __syncthreads();
    }
    unsigned int run = tmp[tid] - tsum;
    if (tid == 255) blk_sums[blockIdx.x] = tmp[255];
#pragma unroll
    for (int i = 0; i < 8; ++i) {
        int idx = base + tid * 8 + i;
        if (idx < n) off[idx] = run;
        run += v[i];
    }
}

__global__ __launch_bounds__(256) void k_scan2(
    const unsigned int* __restrict__ blk_sums, unsigned int* __restrict__ blk_offs,
    unsigned int* __restrict__ off, int nblocks, int n)
{
    __shared__ unsigned int tmp[256];
    int tid = threadIdx.x;
    unsigned int v = (tid < nblocks) ? blk_sums[tid] : 0u;
    tmp[tid] = v; __syncthreads();
    for (int o = 1; o < 256; o <<= 1) {
        unsigned int u = (tid >= o) ? tmp[tid - o] : 0u; __syncthreads();
        tmp[tid] += u; __syncthreads();
    }
    if (tid < nblocks) blk_offs[tid] = tmp[tid] - v;
    if (tid == 255) off[n] = tmp[255];
}

__global__ __launch_bounds__(256) void k_scan3(
    unsigned int* __restrict__ off, unsigned int* __restrict__ cursor,
    const unsigned int* __restrict__ blk_offs, int n)
{
    int i = blockIdx.x * blockDim.x + threadIdx.x;
    if (i < n) {
        unsigned int o = off[i] + blk_offs[i / SCAN_ITEMS];
        off[i] = o; cursor[i] = o;
    }
}

// ---------------------------------------------------------------------------
// Fused weighted gather, single pass:
//   out[d] = sum_e E[src_e] * z[src_e]  /  sum_e E[src_e]
// One wave per dst node; 8 edges in flight (8 lanes/edge, uint4 = 8 bf16/lane).
__global__ __launch_bounds__(256) void k_fused(
    const int* __restrict__ ssrc, const unsigned int* __restrict__ off,
    const float* __restrict__ E, const unsigned short* __restrict__ z16,
    float* __restrict__ out, int n_nodes)
{
    int node = (blockIdx.x * blockDim.x + threadIdx.x) >> 6;
    int lane = threadIdx.x & 63;
    if (node >= n_nodes) return;
    int g  = lane >> 3;   // edge group 0..7
    int fl = lane & 7;    // feature lane: features [8*fl, 8*fl+8)

    unsigned int start = off[node], end = off[node + 1];
    float* orow = out + (size_t)node * D_OUT;
    if (start == end) {   // no in-edges -> 0 (DGL)
        if (g == 0) {
            *(float4*)(orow + fl * 8)     = make_float4(0.f, 0.f, 0.f, 0.f);
            *(float4*)(orow + fl * 8 + 4) = make_float4(0.f, 0.f, 0.f, 0.f);
        }
        return;
    }

    float acc[8];
#pragma unroll
    for (int j = 0; j < 8; ++j) acc[j] = 0.0f;
    float wsum = 0.0f;

    for (unsigned int i = start + g; i < end; i += 8) {
        int sn = ssrc[i];
        float w = E[sn];
        wsum += w;
        const uint4 p = *(const uint4*)(z16 + (size_t)sn * D_OUT + fl * 8);
        const unsigned int pu[4] = {p.x, p.y, p.z, p.w};
#pragma unroll
        for (int q = 0; q < 4; ++q) {
            float lo = __uint_as_float(pu[q] << 16);
            float hi = __uint_as_float(pu[q] & 0xffff0000u);
            acc[2 * q]     = fmaf(w, lo, acc[2 * q]);
            acc[2 * q + 1] = fmaf(w, hi, acc[2 * q + 1]);
        }
    }

#pragma unroll
    for (int o = 8; o <= 32; o <<= 1) {
#pragma unroll
        for (int j = 0; j < 8; ++j) acc[j] += __shfl_xor(acc[j], o, 64);
        wsum += __shfl_xor(wsum, o, 64);
    }

    if (g == 0) {
        float inv = 1.0f / wsum;
        float4 o0 = make_float4(acc[0] * inv, acc[1] * inv, acc[2] * inv, acc[3] * inv);
        float4 o1 = make_float4(acc[4] * inv, acc[5] * inv, acc[6] * inv, acc[7] * inv);
        *(float4*)(orow + fl * 8)     = o0;
        *(float4*)(orow + fl * 8 + 4) = o1;
    }
}

// ---------------------------------------------------------------------------
extern "C" void kernel_launch(void* const* d_in, const int* in_sizes, int n_in,
                              void* d_out, int out_size, void* d_ws, size_t ws_size,
                              hipStream_t stream) {
    const float* h   = (const float*)d_in[0];
    const float* W   = (const float*)d_in[1];
    const float* a   = (const float*)d_in[2];
    const int*   src = (const int*)d_in[3];
    const int*   dst = (const int*)d_in[4];
    float* out = (float*)d_out;

    const int n_nodes = in_sizes[0] / D_IN;   // 100000
    const int n_edges = in_sizes[3];          // 3200000

    const int NB = (n_nodes + (1 << BSHIFT) - 1) >> BSHIFT;   // 391
    const int NT = (n_edges + TILE - 1) / TILE;               // 782
    const size_t histT_elems = (size_t)NB * NT + 1;
    const int n_scan = NB * NT;
    const int sb_sort = (n_scan + SCAN_ITEMS - 1) / SCAN_ITEMS;   // 150

    auto align = [](size_t x) { return (x + 255) & ~(size_t)255; };
    char* w = (char*)d_ws;
    unsigned short* z16 = (unsigned short*)w;  w += align((size_t)n_nodes * D_OUT * sizeof(unsigned short));
    float* E = (float*)w;                      w += align((size_t)n_nodes * sizeof(float));
    unsigned int* off = (unsigned int*)w;      w += align(((size_t)n_nodes + 1) * sizeof(unsigned int));
    unsigned int* blk_sums = (unsigned int*)w; w += align(256 * sizeof(unsigned int));
    unsigned int* blk_offs = (unsigned int*)w; w += align(256 * sizeof(unsigned int));
    size_t hist_region = align(((histT_elems > (size_t)n_nodes ? histT_elems : (size_t)n_nodes)) * sizeof(unsigned int));
    unsigned int* histT = (unsigned int*)w;    w += hist_region;
    unsigned int* count = histT;
    int* ssrc = (int*)w;                       w += align((size_t)n_edges * sizeof(int));
    unsigned int* tmp = (unsigned int*)w;
    unsigned short* rank = (unsigned short*)tmp;
    size_t need_sort = ((char*)tmp - (char*)d_ws) + align((size_t)n_edges * sizeof(unsigned int));
    size_t need_rank = ((char*)tmp - (char*)d_ws) + align((size_t)n_edges * sizeof(unsigned short));

    const bool use_sort = (ws_size >= need_sort) && NB <= MAXNB &&
                          n_nodes < (1 << 24) && sb_sort <= 256;
    const bool use_rank = !use_sort && (ws_size >= need_rank);

    // K1: LDS-tiled projection, 64 nodes per block
    k_project<<<(n_nodes + BN - 1) / BN, 256, 0, stream>>>(h, W, a, z16, E, n_nodes);

    const int eblocks = (n_edges + 255) / 256;
    const int sb_node = (n_nodes + SCAN_ITEMS - 1) / SCAN_ITEMS;   // 49

    if (use_sort) {
        k_hist<<<NT, 256, 0, stream>>>(dst, histT, n_edges, NB, NT);
        k_scan1<<<sb_sort, 256, 0, stream>>>(histT, histT, blk_sums, n_scan);
        k_scan2<<<1, 256, 0, stream>>>(blk_sums, blk_offs, histT, sb_sort, n_scan);
        k_scan3<<<(n_scan + 255) / 256, 256, 0, stream>>>(histT, histT, blk_offs, n_scan);
        k_partition<<<NT, 256, 0, stream>>>(src, dst, histT, tmp, n_edges, NB, NT);
        k_bucket<<<NB, 256, 0, stream>>>(tmp, histT, off, ssrc, n_edges, n_nodes, NB, NT);
    } else if (use_rank) {
        hipMemsetAsync(count, 0, (size_t)n_nodes * sizeof(unsigned int), stream);
        k_rank<<<eblocks, 256, 0, stream>>>(dst, count, rank, n_edges);
        k_scan1<<<sb_node, 256, 0, stream>>>(count, off, blk_sums, n_nodes);
        k_scan2<<<1, 256, 0, stream>>>(blk_sums, blk_offs, off, sb_node, n_nodes);
        k_scan3<<<(n_nodes + 255) / 256, 256, 0, stream>>>(off, count, blk_offs, n_nodes);
        k_place<<<eblocks, 256, 0, stream>>>(src, dst, off, rank, ssrc, n_edges);
    } else {
        hipMemsetAsync(count, 0, (size_t)n_nodes * sizeof(unsigned int), stream);
        k_count<<<eblocks, 256, 0, stream>>>(dst, count, n_edges);
        k_scan1<<<sb_node, 256, 0, stream>>>(count, off, blk_sums, n_nodes);
        k_scan2<<<1, 256, 0, stream>>>(blk_sums, blk_offs, off, sb_node, n_nodes);
        k_scan3<<<(n_nodes + 255) / 256, 256, 0, stream>>>(off, count, blk_offs, n_nodes);
        k_fill<<<eblocks, 256, 0, stream>>>(src, dst, count, ssrc, n_edges);
    }

    // Fused single-pass softmax-weighted gather: one wave per node
    k_fused<<<(n_nodes + 3) / 4, 256, 0, stream>>>(ssrc, off, E, z16, out, n_nodes);
}

// Round 8
// 296.513 us; speedup vs baseline: 4.3778x; 1.0326x over previous
//
#include <hip/hip_runtime.h>

#define D_IN 128
#define D_OUT 64
#define SCAN_ITEMS 2048   // per scan block: 256 threads x 8 items
#define TILE 8192         // edges per partition tile
#define BSHIFT 7          // coarse bucket = dst >> 7 (128 dst per bucket)
#define NBK 128           // nodes per bucket (1 << BSHIFT)
#define MAXNB 1024        // max coarse buckets supported by LDS cursor arrays
#define CAP 8192          // per-bucket LDS edge capacity in k_gather
#define BN 64             // nodes per block in k_project
#define HS_STRIDE 132     // 128 + 4 pad: avoids 4-way LDS bank aliasing

// fp32 -> bf16 (RNE) as ushort
__device__ __forceinline__ unsigned short f32_to_bf16(float f) {
    unsigned int u = __float_as_uint(f);
    u += 0x7fffu + ((u >> 16) & 1u);
    return (unsigned short)(u >> 16);
}

// ---------------------------------------------------------------------------
// K1: LDS-tiled projection GEMM. Block = 256 threads = 64 nodes.
__global__ __launch_bounds__(256) void k_project(
    const float* __restrict__ h, const float* __restrict__ W,
    const float* __restrict__ a, unsigned short* __restrict__ z16,
    float* __restrict__ E, int n_nodes)
{
    __shared__ float ws[D_IN * D_OUT];      // [k][col], 32 KB
    __shared__ float hs[BN * HS_STRIDE];    // [node][k], 33.8 KB

    const int tid = threadIdx.x;
    const int nbase = blockIdx.x * BN;

#pragma unroll
    for (int i = 0; i < 8; ++i) {
        int f = (tid + 256 * i) * 4;
        *(float4*)&ws[f] = *(const float4*)&W[f];
    }
#pragma unroll
    for (int j = 0; j < 8; ++j) {
        int f = tid + 256 * j;              // float4 index
        int row = f >> 5;
        int kk = (f & 31) << 2;
        int gr = nbase + row;
        float4 v = make_float4(0.f, 0.f, 0.f, 0.f);
        if (gr < n_nodes) v = *(const float4*)&h[(size_t)gr * D_IN + kk];
        *(float4*)&hs[row * HS_STRIDE + kk] = v;
    }
    __syncthreads();

    const int c4 = (tid & 15) * 4;
    const int n4 = (tid >> 4) * 4;

    float acc[4][4];
#pragma unroll
    for (int i = 0; i < 4; ++i)
#pragma unroll
        for (int j = 0; j < 4; ++j) acc[i][j] = 0.0f;

    for (int k = 0; k < D_IN; k += 4) {
        float4 wv0 = *(float4*)&ws[(k + 0) * D_OUT + c4];
        float4 wv1 = *(float4*)&ws[(k + 1) * D_OUT + c4];
        float4 wv2 = *(float4*)&ws[(k + 2) * D_OUT + c4];
        float4 wv3 = *(float4*)&ws[(k + 3) * D_OUT + c4];
#pragma unroll
        for (int i = 0; i < 4; ++i) {
            float4 hv = *(float4*)&hs[(n4 + i) * HS_STRIDE + k];
            acc[i][0] = fmaf(hv.x, wv0.x, acc[i][0]);
            acc[i][1] = fmaf(hv.x, wv0.y, acc[i][1]);
            acc[i][2] = fmaf(hv.x, wv0.z, acc[i][2]);
            acc[i][3] = fmaf(hv.x, wv0.w, acc[i][3]);
            acc[i][0] = fmaf(hv.y, wv1.x, acc[i][0]);
            acc[i][1] = fmaf(hv.y, wv1.y, acc[i][1]);
            acc[i][2] = fmaf(hv.y, wv1.z, acc[i][2]);
            acc[i][3] = fmaf(hv.y, wv1.w, acc[i][3]);
            acc[i][0] = fmaf(hv.z, wv2.x, acc[i][0]);
            acc[i][1] = fmaf(hv.z, wv2.y, acc[i][1]);
            acc[i][2] = fmaf(hv.z, wv2.z, acc[i][2]);
            acc[i][3] = fmaf(hv.z, wv2.w, acc[i][3]);
            acc[i][0] = fmaf(hv.w, wv3.x, acc[i][0]);
            acc[i][1] = fmaf(hv.w, wv3.y, acc[i][1]);
            acc[i][2] = fmaf(hv.w, wv3.z, acc[i][2]);
            acc[i][3] = fmaf(hv.w, wv3.w, acc[i][3]);
        }
    }

    float a0 = a[c4 + 0], a1 = a[c4 + 1], a2 = a[c4 + 2], a3 = a[c4 + 3];
#pragma unroll
    for (int i = 0; i < 4; ++i) {
        int node = nbase + n4 + i;
        bool ok = node < n_nodes;
        if (ok) {
            ushort4 q;
            q.x = f32_to_bf16(acc[i][0]);
            q.y = f32_to_bf16(acc[i][1]);
            q.z = f32_to_bf16(acc[i][2]);
            q.w = f32_to_bf16(acc[i][3]);
            *(ushort4*)&z16[(size_t)node * D_OUT + c4] = q;
        }
        float es_p = acc[i][0] * a0 + acc[i][1] * a1 + acc[i][2] * a2 + acc[i][3] * a3;
        es_p += __shfl_xor(es_p, 1, 64);
        es_p += __shfl_xor(es_p, 2, 64);
        es_p += __shfl_xor(es_p, 4, 64);
        es_p += __shfl_xor(es_p, 8, 64);
        if ((tid & 15) == 0 && ok)
            E[node] = __expf(fminf(fmaxf(es_p, -60.0f), 60.0f));
    }
}

// ---------------------------------------------------------------------------
// Counting-sort phase A: per-tile LDS histogram of coarse buckets.
__global__ __launch_bounds__(256) void k_hist(
    const int* __restrict__ dst, unsigned int* __restrict__ histT,
    int n_edges, int NB, int NT)
{
    __shared__ unsigned int hcnt[MAXNB];
    int t = blockIdx.x;
    for (int b = threadIdx.x; b < NB; b += 256) hcnt[b] = 0;
    __syncthreads();
    int base = t * TILE;
    int lim = min(base + TILE, n_edges);
    for (int i = base + threadIdx.x; i < lim; i += 256)
        atomicAdd(&hcnt[(unsigned int)dst[i] >> BSHIFT], 1u);
    __syncthreads();
    for (int b = threadIdx.x; b < NB; b += 256)
        histT[(size_t)b * NT + t] = hcnt[b];
}

// Phase A2: scatter packed (src<<BSHIFT | dstLow) into bucket-grouped tmp.
__global__ __launch_bounds__(256) void k_partition(
    const int* __restrict__ src, const int* __restrict__ dst,
    const unsigned int* __restrict__ histT, unsigned int* __restrict__ tmp,
    int n_edges, int NB, int NT)
{
    __shared__ unsigned int cur[MAXNB];
    int t = blockIdx.x;
    for (int b = threadIdx.x; b < NB; b += 256)
        cur[b] = histT[(size_t)b * NT + t];
    __syncthreads();
    int base = t * TILE;
    int lim = min(base + TILE, n_edges);
    for (int i = base + threadIdx.x; i < lim; i += 256) {
        unsigned int d = (unsigned int)dst[i];
        unsigned int pos = atomicAdd(&cur[d >> BSHIFT], 1u);
        tmp[pos] = ((unsigned int)src[i] << BSHIFT) | (d & (NBK - 1u));
    }
}

// ---------------------------------------------------------------------------
// Fused bucket sub-sort + weighted gather. One block (512 thr, 8 waves) per
// bucket of 128 dst nodes. LDS: hist -> scan -> place edges -> gather from LDS.
__global__ __launch_bounds__(512) void k_gather(
    const unsigned int* __restrict__ tmp, const unsigned int* __restrict__ histT,
    const float* __restrict__ E, const unsigned short* __restrict__ z16,
    int* __restrict__ sscratch, float* __restrict__ out,
    int n_edges, int n_nodes, int NB, int NT)
{
    __shared__ unsigned int offL[NBK + 1];
    __shared__ unsigned int cnt[NBK];
    __shared__ unsigned int sedge[CAP];

    const int b = blockIdx.x;
    const int tid = threadIdx.x;
    const unsigned int s0 = histT[(size_t)b * NT];
    const unsigned int s1 = (b + 1 < NB) ? histT[(size_t)(b + 1) * NT] : (unsigned int)n_edges;
    const unsigned int sz = s1 - s0;
    const bool inLds = (sz <= CAP);

    // phase 1: histogram of dstLow
    if (tid < NBK) cnt[tid] = 0;
    __syncthreads();
    for (unsigned int i = s0 + tid; i < s1; i += 512)
        atomicAdd(&cnt[tmp[i] & (NBK - 1u)], 1u);
    __syncthreads();

    // phase 2: exclusive scan of 128 bins
    unsigned int v = (tid < NBK) ? cnt[tid] : 0u;
    if (tid < NBK) offL[tid] = v;
    __syncthreads();
    for (int o = 1; o < NBK; o <<= 1) {
        unsigned int u = (tid < NBK && tid >= o) ? offL[tid - o] : 0u;
        __syncthreads();
        if (tid < NBK) offL[tid] += u;
        __syncthreads();
    }
    unsigned int excl = (tid < NBK) ? (offL[tid] - v) : 0u;
    __syncthreads();
    if (tid < NBK) { offL[tid] = excl; cnt[tid] = excl; }
    if (tid == 0) offL[NBK] = sz;
    __syncthreads();

    // phase 3: place edges sorted by dstLow (LDS, or global scratch if huge)
    if (inLds) {
        for (unsigned int i = s0 + tid; i < s1; i += 512) {
            unsigned int val = tmp[i];
            unsigned int pos = atomicAdd(&cnt[val & (NBK - 1u)], 1u);
            sedge[pos] = val >> BSHIFT;
        }
    } else {
        for (unsigned int i = s0 + tid; i < s1; i += 512) {
            unsigned int val = tmp[i];
            unsigned int pos = atomicAdd(&cnt[val & (NBK - 1u)], 1u);
            sscratch[s0 + pos] = (int)(val >> BSHIFT);
        }
    }
    __syncthreads();

    // phase 4: per-node weighted gather. Wave w handles dstLow = w, w+8, ...
    const int wave = tid >> 6;
    const int lane = tid & 63;
    const int g = lane >> 3;    // edge group 0..7
    const int fl = lane & 7;    // feature lane: features [8*fl, 8*fl+8)

    for (int dl = wave; dl < NBK; dl += 8) {
        int node = (b << BSHIFT) + dl;
        if (node >= n_nodes) break;
        unsigned int a0 = offL[dl], a1 = offL[dl + 1];
        float* orow = out + (size_t)node * D_OUT;
        if (a0 == a1) {          // no in-edges -> 0 (DGL)
            if (g == 0) {
                *(float4*)(orow + fl * 8)     = make_float4(0.f, 0.f, 0.f, 0.f);
                *(float4*)(orow + fl * 8 + 4) = make_float4(0.f, 0.f, 0.f, 0.f);
            }
            continue;
        }

        float acc[8];
#pragma unroll
        for (int j = 0; j < 8; ++j) acc[j] = 0.0f;
        float wsum = 0.0f;

        for (unsigned int i = a0 + g; i < a1; i += 8) {
            int sn = inLds ? (int)sedge[i] : sscratch[s0 + i];
            float wgt = E[sn];
            wsum += wgt;
            const uint4 p = *(const uint4*)(z16 + (size_t)sn * D_OUT + fl * 8);
            const unsigned int pu[4] = {p.x, p.y, p.z, p.w};
#pragma unroll
            for (int q = 0; q < 4; ++q) {
                float lo = __uint_as_float(pu[q] << 16);
                float hi = __uint_as_float(pu[q] & 0xffff0000u);
                acc[2 * q]     = fmaf(wgt, lo, acc[2 * q]);
                acc[2 * q + 1] = fmaf(wgt, hi, acc[2 * q + 1]);
            }
        }

#pragma unroll
        for (int o = 8; o <= 32; o <<= 1) {
#pragma unroll
            for (int j = 0; j < 8; ++j) acc[j] += __shfl_xor(acc[j], o, 64);
            wsum += __shfl_xor(wsum, o, 64);
        }

        if (g == 0) {
            float inv = 1.0f / wsum;
            float4 o0 = make_float4(acc[0] * inv, acc[1] * inv, acc[2] * inv, acc[3] * inv);
            float4 o1 = make_float4(acc[4] * inv, acc[5] * inv, acc[6] * inv, acc[7] * inv);
            *(float4*)(orow + fl * 8)     = o0;
            *(float4*)(orow + fl * 8 + 4) = o1;
        }
    }
}

// ---------------------------------------------------------------------------
// Fallback kernels (small ws): atomic rank / fill paths + per-node fused gather.
__global__ __launch_bounds__(256) void k_rank(
    const int* __restrict__ dst, unsigned int* __restrict__ count,
    unsigned short* __restrict__ rank, int n_edges)
{
    int e = blockIdx.x * blockDim.x + threadIdx.x;
    if (e < n_edges) rank[e] = (unsigned short)atomicAdd(&count[dst[e]], 1u);
}

__global__ __launch_bounds__(256) void k_place(
    const int* __restrict__ src, const int* __restrict__ dst,
    const unsigned int* __restrict__ off, const unsigned short* __restrict__ rank,
    int* __restrict__ ssrc, int n_edges)
{
    int e = blockIdx.x * blockDim.x + threadIdx.x;
    if (e < n_edges) ssrc[off[dst[e]] + (unsigned int)rank[e]] = src[e];
}

__global__ __launch_bounds__(256) void k_count(
    const int* __restrict__ dst, unsigned int* __restrict__ count, int n_edges)
{
    int e = blockIdx.x * blockDim.x + threadIdx.x;
    if (e < n_edges) atomicAdd(&count[dst[e]], 1u);
}

__global__ __launch_bounds__(256) void k_fill(
    const int* __restrict__ src, const int* __restrict__ dst,
    unsigned int* __restrict__ cursor, int* __restrict__ ssrc, int n_edges)
{
    int e = blockIdx.x * blockDim.x + threadIdx.x;
    if (e < n_edges) {
        unsigned int pos = atomicAdd(&cursor[dst[e]], 1u);
        ssrc[pos] = src[e];
    }
}

__global__ __launch_bounds__(256) void k_fused(
    const int* __restrict__ ssrc, const unsigned int* __restrict__ off,
    const float* __restrict__ E, const unsigned short* __restrict__ z16,
    float* __restrict__ out, int n_nodes)
{
    int node = (blockIdx.x * blockDim.x + threadIdx.x) >> 6;
    int lane = threadIdx.x & 63;
    if (node >= n_nodes) return;
    int g  = lane >> 3;
    int fl = lane & 7;

    unsigned int start = off[node], end = off[node + 1];
    float* orow = out + (size_t)node * D_OUT;
    if (start == end) {
        if (g == 0) {
            *(float4*)(orow + fl * 8)     = make_float4(0.f, 0.f, 0.f, 0.f);
            *(float4*)(orow + fl * 8 + 4) = make_float4(0.f, 0.f, 0.f, 0.f);
        }
        return;
    }

    float acc[8];
#pragma unroll
    for (int j = 0; j < 8; ++j) acc[j] = 0.0f;
    float wsum = 0.0f;

    for (unsigned int i = start + g; i < end; i += 8) {
        int sn = ssrc[i];
        float w = E[sn];
        wsum += w;
        const uint4 p = *(const uint4*)(z16 + (size_t)sn * D_OUT + fl * 8);
        const unsigned int pu[4] = {p.x, p.y, p.z, p.w};
#pragma unroll
        for (int q = 0; q < 4; ++q) {
            float lo = __uint_as_float(pu[q] << 16);
            float hi = __uint_as_float(pu[q] & 0xffff0000u);
            acc[2 * q]     = fmaf(w, lo, acc[2 * q]);
            acc[2 * q + 1] = fmaf(w, hi, acc[2 * q + 1]);
        }
    }

#pragma unroll
    for (int o = 8; o <= 32; o <<= 1) {
#pragma unroll
        for (int j = 0; j < 8; ++j) acc[j] += __shfl_xor(acc[j], o, 64);
        wsum += __shfl_xor(wsum, o, 64);
    }

    if (g == 0) {
        float inv = 1.0f / wsum;
        float4 o0 = make_float4(acc[0] * inv, acc[1] * inv, acc[2] * inv, acc[3] * inv);
        float4 o1 = make_float4(acc[4] * inv, acc[5] * inv, acc[6] * inv, acc[7] * inv);
        *(float4*)(orow + fl * 8)     = o0;
        *(float4*)(orow + fl * 8 + 4) = o1;
    }
}

// ---------------------------------------------------------------------------
// Exclusive scan (3 levels). scan1 is safe in-place.
__global__ __launch_bounds__(256) void k_scan1(
    const unsigned int* __restrict__ count, unsigned int* __restrict__ off,
    unsigned int* __restrict__ blk_sums, int n)
{
    __shared__ unsigned int tmp[256];
    int tid = threadIdx.x;
    int base = blockIdx.x * SCAN_ITEMS;
    unsigned int v[8]; unsigned int tsum = 0;
#pragma unroll
    for (int i = 0; i < 8; ++i) {
        int idx = base + tid * 8 + i;
        v[i] = (idx < n) ? count[idx] : 0u;
        tsum += v[i];
    }
    tmp[tid] = tsum; __syncthreads();
    for (int o = 1; o < 256; o <<= 1) {
        unsigned int u = (tid >= o) ? tmp[tid - o] : 0u; __syncthreads();
        tmp[tid] += u; __syncthreads();
    }
    unsigned int run = tmp[tid] - tsum;
    if (tid == 255) blk_sums[blockIdx.x] = tmp[255];
#pragma unroll
    for (int i = 0; i < 8; ++i) {
        int idx = base + tid * 8 + i;
        if (idx < n) off[idx] = run;
        run += v[i];
    }
}

__global__ __launch_bounds__(256) void k_scan2(
    const unsigned int* __restrict__ blk_sums, unsigned int* __restrict__ blk_offs,
    unsigned int* __restrict__ off, int nblocks, int n)
{
    __shared__ unsigned int tmp[256];
    int tid = threadIdx.x;
    unsigned int v = (tid < nblocks) ? blk_sums[tid] : 0u;
    tmp[tid] = v; __syncthreads();
    for (int o = 1; o < 256; o <<= 1) {
        unsigned int u = (tid >= o) ? tmp[tid - o] : 0u; __syncthreads();
        tmp[tid] += u; __syncthreads();
    }
    if (tid < nblocks) blk_offs[tid] = tmp[tid] - v;
    if (tid == 255) off[n] = tmp[255];
}

__global__ __launch_bounds__(256) void k_scan3(
    unsigned int* __restrict__ off, unsigned int* __restrict__ cursor,
    const unsigned int* __restrict__ blk_offs, int n)
{
    int i = blockIdx.x * blockDim.x + threadIdx.x;
    if (i < n) {
        unsigned int o = off[i] + blk_offs[i / SCAN_ITEMS];
        off[i] = o; cursor[i] = o;
    }
}

// ---------------------------------------------------------------------------
extern "C" void kernel_launch(void* const* d_in, const int* in_sizes, int n_in,
                              void* d_out, int out_size, void* d_ws, size_t ws_size,
                              hipStream_t stream) {
    const float* h   = (const float*)d_in[0];
    const float* W   = (const float*)d_in[1];
    const float* a   = (const float*)d_in[2];
    const int*   src = (const int*)d_in[3];
    const int*   dst = (const int*)d_in[4];
    float* out = (float*)d_out;

    const int n_nodes = in_sizes[0] / D_IN;   // 100000
    const int n_edges = in_sizes[3];          // 3200000

    const int NB = (n_nodes + NBK - 1) >> BSHIFT;             // 782
    const int NT = (n_edges + TILE - 1) / TILE;               // 391
    const size_t histT_elems = (size_t)NB * NT + 1;
    const int n_scan = NB * NT;
    const int sb_sort = (n_scan + SCAN_ITEMS - 1) / SCAN_ITEMS;   // 150

    auto align = [](size_t x) { return (x + 255) & ~(size_t)255; };
    char* w = (char*)d_ws;
    unsigned short* z16 = (unsigned short*)w;  w += align((size_t)n_nodes * D_OUT * sizeof(unsigned short));
    float* E = (float*)w;                      w += align((size_t)n_nodes * sizeof(float));
    unsigned int* off = (unsigned int*)w;      w += align(((size_t)n_nodes + 1) * sizeof(unsigned int));
    unsigned int* blk_sums = (unsigned int*)w; w += align(256 * sizeof(unsigned int));
    unsigned int* blk_offs = (unsigned int*)w; w += align(256 * sizeof(unsigned int));
    size_t hist_region = align(((histT_elems > (size_t)n_nodes ? histT_elems : (size_t)n_nodes)) * sizeof(unsigned int));
    unsigned int* histT = (unsigned int*)w;    w += hist_region;
    unsigned int* count = histT;
    int* ssrc = (int*)w;                       w += align((size_t)n_edges * sizeof(int));
    unsigned int* tmp = (unsigned int*)w;
    unsigned short* rank = (unsigned short*)tmp;
    size_t need_sort = ((char*)tmp - (char*)d_ws) + align((size_t)n_edges * sizeof(unsigned int));
    size_t need_rank = ((char*)tmp - (char*)d_ws) + align((size_t)n_edges * sizeof(unsigned short));

    const bool use_sort = (ws_size >= need_sort) && NB <= MAXNB &&
                          n_nodes < (1 << 25) && sb_sort <= 256;
    const bool use_rank = !use_sort && (ws_size >= need_rank);

    // K1: LDS-tiled projection, 64 nodes per block
    k_project<<<(n_nodes + BN - 1) / BN, 256, 0, stream>>>(h, W, a, z16, E, n_nodes);

    const int eblocks = (n_edges + 255) / 256;
    const int sb_node = (n_nodes + SCAN_ITEMS - 1) / SCAN_ITEMS;

    if (use_sort) {
        k_hist<<<NT, 256, 0, stream>>>(dst, histT, n_edges, NB, NT);
        k_scan1<<<sb_sort, 256, 0, stream>>>(histT, histT, blk_sums, n_scan);
        k_scan2<<<1, 256, 0, stream>>>(blk_sums, blk_offs, histT, sb_sort, n_scan);
        k_scan3<<<(n_scan + 255) / 256, 256, 0, stream>>>(histT, histT, blk_offs, n_scan);
        k_partition<<<NT, 256, 0, stream>>>(src, dst, histT, tmp, n_edges, NB, NT);
        // fused bucket sub-sort + gather (writes out directly)
        k_gather<<<NB, 512, 0, stream>>>(tmp, histT, E, z16, ssrc, out,
                                         n_edges, n_nodes, NB, NT);
    } else if (use_rank) {
        hipMemsetAsync(count, 0, (size_t)n_nodes * sizeof(unsigned int), stream);
        k_rank<<<eblocks, 256, 0, stream>>>(dst, count, rank, n_edges);
        k_scan1<<<sb_node, 256, 0, stream>>>(count, off, blk_sums, n_nodes);
        k_scan2<<<1, 256, 0, stream>>>(blk_sums, blk_offs, off, sb_node, n_nodes);
        k_scan3<<<(n_nodes + 255) / 256, 256, 0, stream>>>(off, count, blk_offs, n_nodes);
        k_place<<<eblocks, 256, 0, stream>>>(src, dst, off, rank, ssrc, n_edges);
        k_fused<<<(n_nodes + 3) / 4, 256, 0, stream>>>(ssrc, off, E, z16, out, n_nodes);
    } else {
        hipMemsetAsync(count, 0, (size_t)n_nodes * sizeof(unsigned int), stream);
        k_count<<<eblocks, 256, 0, stream>>>(dst, count, n_edges);
        k_scan1<<<sb_node, 256, 0, stream>>>(count, off, blk_sums, n_nodes);
        k_scan2<<<1, 256, 0, stream>>>(blk_sums, blk_offs, off, sb_node, n_nodes);
        k_scan3<<<(n_nodes + 255) / 256, 256, 0, stream>>>(off, count, blk_offs, n_nodes);
        k_fill<<<eblocks, 256, 0, stream>>>(src, dst, count, ssrc, n_edges);
        k_fused<<<(n_nodes + 3) / 4, 256, 0, stream>>>(ssrc, off, E, z16, out, n_nodes);
    }
}